// Round 6
// baseline (301.859 us; speedup 1.0000x reference)
//
#include <hip/hip_runtime.h>
#include <hip/hip_bf16.h>

typedef unsigned short u16;
typedef unsigned int u32;
typedef unsigned long long u64;
typedef __attribute__((ext_vector_type(8))) short short8;   // 8 bf16 = 4 VGPR (MFMA A/B frag)
typedef __attribute__((ext_vector_type(4))) float floatx4;  // MFMA C/D frag
typedef const __attribute__((address_space(1))) void* gp_t; // global ptr for DMA
typedef __attribute__((address_space(3))) void* sp_t;       // LDS ptr for DMA

static __device__ __forceinline__ u16 f2bf(float x) {
    __hip_bfloat16 h = __float2bfloat16(x);
    union { __hip_bfloat16 h; u16 u; } cv; cv.h = h; return cv.u;
}
static __device__ __forceinline__ float bf2f(u16 u) {
    union { u16 u; __hip_bfloat16 h; } cv; cv.u = u;
    return __bfloat162float(cv.h);
}

// ------------- fused prep: adj bitmask + feats fp32->bf16 convert -------------
__global__ void k_prep(const float* __restrict__ feats, const float* __restrict__ adj,
                       u16* __restrict__ featsB, u64* __restrict__ m) {
    long i = (long)blockIdx.x * 256 + threadIdx.x;
    float v = adj[i];
    u64 bm = __ballot(v > 0.f);
    if ((threadIdx.x & 63) == 0) m[i >> 6] = bm;
    if (blockIdx.x < 2048) {
        int j = (blockIdx.x * 256 + threadIdx.x) * 4;
        float4 f = *(const float4*)&feats[j];
        featsB[j + 0] = f2bf(f.x); featsB[j + 1] = f2bf(f.y);
        featsB[j + 2] = f2bf(f.z); featsB[j + 3] = f2bf(f.w);
    }
}

// ---------- tiled transpose fp32[R][C] -> bf16[C][R] (weight prep) ----------
__global__ void k_transpose(const float* __restrict__ in, u16* __restrict__ out,
                            int R, int Cn) {
    __shared__ float t[64][65];
    int c  = threadIdx.x & 63;
    int r0 = threadIdx.x >> 6;
    int bx = blockIdx.x, by = blockIdx.y;
    for (int rr = r0; rr < 64; rr += 4)
        t[rr][c] = in[(long)(by * 64 + rr) * Cn + bx * 64 + c];
    __syncthreads();
    for (int rr = r0; rr < 64; rr += 4)
        out[(long)(bx * 64 + rr) * R + by * 64 + c] = f2bf(t[c][rr]);
}

// ---- effective q/k weights (bf16): W[h_or_k][d] = fc_w[d, h*256:+256]@q_w ----
__global__ void k_wqk(const float* __restrict__ fc_w, const float* __restrict__ fc_b,
                      const float* __restrict__ q_w, const float* __restrict__ q_b,
                      const float* __restrict__ k_w, const float* __restrict__ k_b,
                      u16* __restrict__ W, float* __restrict__ C) {
    int h = blockIdx.x & 7, kind = blockIdx.x >> 3;
    int d = threadIdx.x;
    const float* w = kind ? k_w : q_w;
    __shared__ float ws_[256];
    ws_[d] = w[d];
    __syncthreads();
    const float* row = fc_w + (long)d * 2048 + h * 256;
    float a = 0.f;
    for (int i = 0; i < 256; i++) a += row[i] * ws_[i];
    W[(long)blockIdx.x * 256 + d] = f2bf(a);
    if (d == 0) {
        float cb = 0.f;
        const float* fb = fc_b + h * 256;
        for (int i = 0; i < 256; i++) cb += fb[i] * ws_[i];
        C[blockIdx.x] = cb + (kind ? k_b[0] : q_b[0]);
    }
}

// ---- q/k via MFMA: [8192 rows] x [16 eff cols], K=256, frags from global ----
__global__ __launch_bounds__(256)
void k_qkm(const u16* __restrict__ featsB, const u16* __restrict__ Wb,
           const float* __restrict__ C,
           float* __restrict__ qo, float* __restrict__ ko) {
    int tid = threadIdx.x;
    int wave = tid >> 6, lane = tid & 63;
    int q = lane >> 4, n16 = lane & 15;
    int rowBase = blockIdx.x * 64 + wave * 16;
    const u16* arow = featsB + (long)(rowBase + n16) * 256 + q * 8;
    const u16* brow = Wb + n16 * 256 + q * 8;
    floatx4 acc = {};
    #pragma unroll
    for (int k0 = 0; k0 < 256; k0 += 32) {
        short8 af = *(const short8*)&arow[k0];
        short8 bf = *(const short8*)&brow[k0];
        acc = __builtin_amdgcn_mfma_f32_16x16x32_bf16(af, bf, acc, 0, 0, 0);
    }
    float cc = C[n16];
    #pragma unroll
    for (int r = 0; r < 4; r++) {
        int gr = rowBase + q * 4 + r;
        int b = gr >> 10, nn = gr & 1023;
        float v = acc[r] + cc;
        if (n16 < 8) qo[((b * 8 + n16) << 10) + nn] = v;
        else         ko[((b * 8 + (n16 - 8)) << 10) + nn] = v;
    }
}

// ---------------- templated NT bf16 GEMM: C = A[M][K] * Bt[N][K]^T -----------
template <int EPI, int BM, int BN, int WM, int WN>
__global__ __launch_bounds__(256, 2)
void gemm_nt(const u16* __restrict__ A, const u16* __restrict__ Bt,
             int lda, int ldb, int K,
             void* __restrict__ Cv,
             const float* __restrict__ bias,
             const float* __restrict__ resid) {
    __shared__ u16 As[BM * 40];
    __shared__ u16 Bs[BN * 40];
    int rowBase = blockIdx.y * BM;
    int colBase = blockIdx.x * BN;
    int tid  = threadIdx.x;
    int wave = tid >> 6, lane = tid & 63;
    int wr = wave >> 1, wc = wave & 1;
    int q  = lane >> 4, n16 = lane & 15;

    floatx4 acc[WM][WN] = {};

    int sm = tid >> 2;          // 0..63 staging row
    int sk = (tid & 3) * 8;     // k-chunk within BK=32

    for (int k0 = 0; k0 < K; k0 += 32) {
        int4 al[BM / 64], bl[BN / 64];
        #pragma unroll
        for (int r = 0; r < BM / 64; r++)
            al[r] = *(const int4*)&A[(long)(rowBase + sm + 64 * r) * lda + k0 + sk];
        #pragma unroll
        for (int r = 0; r < BN / 64; r++)
            bl[r] = *(const int4*)&Bt[(long)(colBase + sm + 64 * r) * ldb + k0 + sk];
        __syncthreads();   // previous iter's frag reads done
        #pragma unroll
        for (int r = 0; r < BM / 64; r++)
            *(int4*)&As[(sm + 64 * r) * 40 + sk] = al[r];
        #pragma unroll
        for (int r = 0; r < BN / 64; r++)
            *(int4*)&Bs[(sm + 64 * r) * 40 + sk] = bl[r];
        __syncthreads();
        short8 af[WM], bfr[WN];
        #pragma unroll
        for (int i = 0; i < WM; i++)
            af[i] = *(short8*)&As[(wr * WM * 16 + i * 16 + n16) * 40 + q * 8];
        #pragma unroll
        for (int i = 0; i < WN; i++)
            bfr[i] = *(short8*)&Bs[(wc * WN * 16 + i * 16 + n16) * 40 + q * 8];
        #pragma unroll
        for (int mi = 0; mi < WM; mi++)
            #pragma unroll
            for (int ni = 0; ni < WN; ni++)
                acc[mi][ni] = __builtin_amdgcn_mfma_f32_16x16x32_bf16(
                    af[mi], bfr[ni], acc[mi][ni], 0, 0, 0);
    }

    u16*   Cb = (u16*)Cv;
    float* Cf = (float*)Cv;
    #pragma unroll
    for (int mi = 0; mi < WM; mi++) {
        #pragma unroll
        for (int r = 0; r < 4; r++) {
            int grow = rowBase + wr * WM * 16 + mi * 16 + q * 4 + r;
            #pragma unroll
            for (int ni = 0; ni < WN; ni++) {
                int gcol = colBase + wc * WN * 16 + ni * 16 + n16;
                float v = acc[mi][ni][r];
                if (EPI == 1) {
                    v += bias[grow];                   // bias over hd rows
                    int b = gcol >> 10, nn = gcol & 1023;
                    Cb[(((long)(b * 2048 + grow)) << 10) + nn] = f2bf(v);
                } else {
                    v += bias[gcol] + resid[(long)grow * 256 + gcol];
                    Cf[(long)grow * 256 + gcol] = 1.f / (1.f + __expf(-v));
                }
            }
        }
    }
}

// -------- fused attention v4: out_h = softmax(adj*exp(leaky(q+k))) @ V --------
// grid dim3(64, 8): x = bh, y = i-tile. Same-bh blocks have linear ids
// z + 64k === z (mod 8) -> same XCD -> V (0.5 MB/bh) stays in that XCD's L2
// instead of being re-fetched from HBM by 8 different XCDs (round-5 FETCH
// was 133 MB, ~4x V's one-pass 33.5 MB).
// P packed to bf16 by TRUNCATION (3 ops/pair vs ~10 for RNE); lsum sums the
// truncated values so softmax numerator/denominator stay consistent.
__global__ __launch_bounds__(256)
__attribute__((amdgpu_waves_per_eu(2)))
void k_attn(const u32* __restrict__ maskW, const float* __restrict__ qv,
            const float* __restrict__ kv, const u16* __restrict__ fpjT,
            u16* __restrict__ outh) {
    __shared__ u16 As[2][128 * 40];       // P-tiles 128 x 32, stride 40
    __shared__ u16 Bs[2][256 * 32];       // V^T tiles 256(d) x 32(j), DMA target
    __shared__ float qS[128], kS[1024], lsumS[256], rlS[128];

    int z = blockIdx.x;                   // bh  (XCD = z % 8)
    int b = z >> 3, h = z & 7;
    int i0 = blockIdx.y * 128;
    int tid = threadIdx.x;
    int wave = tid >> 6, lane = tid & 63;
    int wr = wave >> 1, wc = wave & 1;
    int q  = lane >> 4, n16 = lane & 15;

    *(float4*)&kS[tid * 4] = *(const float4*)&kv[(z << 10) + tid * 4];
    if (tid < 128) qS[tid] = qv[(z << 10) + i0 + tid];

    floatx4 acc[4][8] = {};
    int ar = tid >> 1;                    // P row (0..127)
    int jq = (tid & 1) * 16;              // P j-offset within BK (16 elems each)
    const u32* mrow = maskW + (((long)(b << 10) + i0 + ar) << 5);
    const u16* Vbase = fpjT + ((long)z << 18);
    int vrow = wave * 64 + (lane >> 2);   // DMA: wave covers 64 V rows
    int vchk = (lane & 3) * 8;
    float lsum = 0.f;

    auto dma_v = [&](int k0, int p) {
        #pragma unroll
        for (int t = 0; t < 4; t++)
            __builtin_amdgcn_global_load_lds(
                (gp_t)&Vbase[(long)(vrow + t * 16) * 1024 + k0 + vchk],
                (sp_t)&Bs[p][(wave * 64 + t * 16) * 32],
                16, 0, 0);
    };
    auto stage_p = [&](int k0, int p) {
        u32 mw = mrow[k0 >> 5] >> jq;     // 16 mask bits for this thread
        float qi = qS[ar];
        float lkk[16];
        *(float4*)&lkk[0]  = *(const float4*)&kS[k0 + jq + 0];
        *(float4*)&lkk[4]  = *(const float4*)&kS[k0 + jq + 4];
        *(float4*)&lkk[8]  = *(const float4*)&kS[k0 + jq + 8];
        *(float4*)&lkk[12] = *(const float4*)&kS[k0 + jq + 12];
        u32 pw[8];
        #pragma unroll
        for (int e2 = 0; e2 < 8; e2++) {
            float s0 = qi + lkk[2 * e2];
            s0 = s0 > 0.f ? s0 : 0.01f * s0;
            float p0 = ((mw >> (2 * e2)) & 1u) ? __expf(s0) : 0.f;
            float s1 = qi + lkk[2 * e2 + 1];
            s1 = s1 > 0.f ? s1 : 0.01f * s1;
            float p1 = ((mw >> (2 * e2 + 1)) & 1u) ? __expf(s1) : 0.f;
            u32 t0 = __float_as_uint(p0) & 0xFFFF0000u;   // bf16 truncation
            u32 t1 = __float_as_uint(p1) & 0xFFFF0000u;
            lsum += __uint_as_float(t0) + __uint_as_float(t1);
            pw[e2] = (t0 >> 16) | t1;
        }
        *(int4*)&As[p][ar * 40 + jq]     = *(int4*)&pw[0];
        *(int4*)&As[p][ar * 40 + jq + 8] = *(int4*)&pw[4];
    };

    __syncthreads();                      // qS/kS visible
    dma_v(0, 0);
    stage_p(0, 0);
    __syncthreads();                      // iter 0 staged (DMA drained here)

    for (int k0 = 0; k0 < 1024; k0 += 32) {
        int p = (k0 >> 5) & 1;
        short8 af[4], bfr[8];
        #pragma unroll
        for (int i = 0; i < 4; i++)
            af[i] = *(short8*)&As[p][(wr * 64 + i * 16 + n16) * 40 + q * 8];
        #pragma unroll
        for (int i = 0; i < 8; i++)
            bfr[i] = *(short8*)&Bs[p][(wc * 128 + i * 16 + n16) * 32 + q * 8];
        if (k0 + 32 < 1024) {
            dma_v(k0 + 32, p ^ 1);
            stage_p(k0 + 32, p ^ 1);
        }
        #pragma unroll
        for (int mi = 0; mi < 4; mi++)
            #pragma unroll
            for (int ni = 0; ni < 8; ni++)
                acc[mi][ni] = __builtin_amdgcn_mfma_f32_16x16x32_bf16(
                    af[mi], bfr[ni], acc[mi][ni], 0, 0, 0);
        __syncthreads();                  // next buffer staged + DMA drained
    }

    // row-sum: 2 threads per row
    lsumS[tid] = lsum;
    __syncthreads();
    if (tid < 128) {
        float l = lsumS[2 * tid] + lsumS[2 * tid + 1];
        rlS[tid] = l > 0.f ? 1.f / l : 0.f;
    }
    __syncthreads();

    #pragma unroll
    for (int mi = 0; mi < 4; mi++) {
        #pragma unroll
        for (int r = 0; r < 4; r++) {
            int grow = wr * 64 + mi * 16 + q * 4 + r;
            float s = rlS[grow];
            long base = (long)(b * 1024 + i0 + grow) * 2048 + h * 256;
            #pragma unroll
            for (int ni = 0; ni < 8; ni++) {
                int gcol = wc * 128 + ni * 16 + n16;
                outh[base + gcol] = f2bf(acc[mi][ni][r] * s);
            }
        }
    }
}

extern "C" void kernel_launch(void* const* d_in, const int* in_sizes, int n_in,
                              void* d_out, int out_size, void* d_ws, size_t ws_size,
                              hipStream_t stream) {
    const float* feats = (const float*)d_in[0];
    const float* adj   = (const float*)d_in[1];
    const float* fc_w  = (const float*)d_in[2];
    const float* fc_b  = (const float*)d_in[3];
    const float* q_w   = (const float*)d_in[4];
    const float* q_b   = (const float*)d_in[5];
    const float* k_w   = (const float*)d_in[6];
    const float* k_b   = (const float*)d_in[7];
    const float* fp_w  = (const float*)d_in[8];
    const float* fp_b  = (const float*)d_in[9];

    char* ws = (char*)d_ws;
    u16*   featsB = (u16*)ws;   ws += (size_t)2097152 * 2;   // [8192][256] bf16
    u16*   fcwT   = (u16*)ws;   ws += (size_t)524288 * 2;    // [2048][256] bf16
    u16*   fpwT   = (u16*)ws;   ws += (size_t)524288 * 2;    // [256][2048] bf16
    u16*   fpjT   = (u16*)ws;   ws += (size_t)16777216 * 2;  // [b,hd,n] bf16
    float* qv     = (float*)ws; ws += (size_t)65536 * 4;     // [b,h,n]
    float* kv     = (float*)ws; ws += (size_t)65536 * 4;
    u16*   outh   = (u16*)ws;   ws += (size_t)16777216 * 2;  // [(b,n)][(h,d)] bf16
    u64*   maskB  = (u64*)ws;   ws += (size_t)131072 * 8;    // adj bits, 1 MB
    u16*   Weff   = (u16*)ws;   ws += (size_t)4096 * 2;      // [16][256] bf16
    float* Ceff   = (float*)ws; ws += (size_t)16 * 4;        // per-head consts

    // prep: feats->bf16 + adj bitmask (fused), weight transposes, eff q/k w
    k_prep<<<32768, 256, 0, stream>>>(feats, adj, featsB, maskB);
    k_transpose<<<dim3(32, 4), 256, 0, stream>>>(fc_w, fcwT, 256, 2048);
    k_transpose<<<dim3(4, 32), 256, 0, stream>>>(fp_w, fpwT, 2048, 256);
    k_wqk<<<16, 256, 0, stream>>>(fc_w, fc_b, q_w, q_b, k_w, k_b, Weff, Ceff);

    // q, k via MFMA from feats + effective weights
    k_qkm<<<128, 256, 0, stream>>>(featsB, Weff, Ceff, qv, kv);

    // G1 (swapped orientation): fpjT[hd][n] = fc_w^T @ feats^T, coalesced store
    gemm_nt<1, 128, 128, 4, 4><<<dim3(64, 16), 256, 0, stream>>>(
        fcwT, featsB, 256, 256, 256, (void*)fpjT, fc_b, nullptr);

    // fused scores + P@V + 1/l scaling (XCD-swizzled: x=bh)
    k_attn<<<dim3(64, 8), 256, 0, stream>>>((const u32*)maskB, qv, kv, fpjT, outh);

    // G3: sigmoid(outh @ fp_w + fp_b + feats), BN=128 halves A re-reads
    gemm_nt<3, 64, 128, 2, 4><<<dim3(2, 128), 256, 0, stream>>>(
        outh, fpwT, 2048, 2048, 2048, d_out, fp_b, feats);
}

// Round 7
// 233.178 us; speedup vs baseline: 1.2945x; 1.2945x over previous
//
#include <hip/hip_runtime.h>
#include <hip/hip_bf16.h>

typedef unsigned short u16;
typedef unsigned int u32;
typedef unsigned long long u64;
typedef __attribute__((ext_vector_type(8))) short short8;   // 8 bf16 = 4 VGPR (MFMA A/B frag)
typedef __attribute__((ext_vector_type(4))) float floatx4;  // MFMA C/D frag
typedef const __attribute__((address_space(1))) void* gp_t; // global ptr for DMA
typedef __attribute__((address_space(3))) void* sp_t;       // LDS ptr for DMA

#define LOG2E 1.44269504088896f

static __device__ __forceinline__ u16 f2bf(float x) {
    __hip_bfloat16 h = __float2bfloat16(x);
    union { __hip_bfloat16 h; u16 u; } cv; cv.h = h; return cv.u;
}
static __device__ __forceinline__ float bf2f(u16 u) {
    union { u16 u; __hip_bfloat16 h; } cv; cv.u = u;
    return __bfloat162float(cv.h);
}

// ------------- fused prep: adj bitmask + feats fp32->bf16 convert -------------
__global__ void k_prep(const float* __restrict__ feats, const float* __restrict__ adj,
                       u16* __restrict__ featsB, u64* __restrict__ m) {
    long i = (long)blockIdx.x * 256 + threadIdx.x;
    float v = adj[i];
    u64 bm = __ballot(v > 0.f);
    if ((threadIdx.x & 63) == 0) m[i >> 6] = bm;
    if (blockIdx.x < 2048) {
        int j = (blockIdx.x * 256 + threadIdx.x) * 4;
        float4 f = *(const float4*)&feats[j];
        featsB[j + 0] = f2bf(f.x); featsB[j + 1] = f2bf(f.y);
        featsB[j + 2] = f2bf(f.z); featsB[j + 3] = f2bf(f.w);
    }
}

// ---------- tiled transpose fp32[R][C] -> bf16[C][R] (fc_w prep) ----------
__global__ void k_transpose(const float* __restrict__ in, u16* __restrict__ out,
                            int R, int Cn) {
    __shared__ float t[64][65];
    int c  = threadIdx.x & 63;
    int r0 = threadIdx.x >> 6;
    int bx = blockIdx.x, by = blockIdx.y;
    for (int rr = r0; rr < 64; rr += 4)
        t[rr][c] = in[(long)(by * 64 + rr) * Cn + bx * 64 + c];
    __syncthreads();
    for (int rr = r0; rr < 64; rr += 4)
        out[(long)(bx * 64 + rr) * R + by * 64 + c] = f2bf(t[c][rr]);
}

// ---- fp_w [2048 k][256 col] -> k-grouped bf16 B2[k>>3][col][k&7] ----
__global__ void k_t2(const float* __restrict__ fp_w, u16* __restrict__ B2) {
    int k = blockIdx.x;           // 0..2047
    int col = threadIdx.x;        // 0..255
    float v = fp_w[(long)k * 256 + col];
    B2[((long)(k >> 3)) * 2048 + col * 8 + (k & 7)] = f2bf(v);
}

// ---- effective q/k weights (bf16): W[x][d] = fc_w[d, h*256:+256]@{q,k}_w ----
// grid (16, 4): x = kind*8+h, y = d-quarter. 4 threads per d, shfl reduce.
__global__ void k_wqk(const float* __restrict__ fc_w, const float* __restrict__ fc_b,
                      const float* __restrict__ q_w, const float* __restrict__ q_b,
                      const float* __restrict__ k_w, const float* __restrict__ k_b,
                      u16* __restrict__ W, float* __restrict__ C) {
    int x = blockIdx.x;
    int h = x & 7, kind = x >> 3;
    int dq = blockIdx.y;
    const float* w = kind ? k_w : q_w;
    __shared__ float ws_[256];
    ws_[threadIdx.x] = w[threadIdx.x];
    __syncthreads();
    int dl = threadIdx.x >> 2, part = threadIdx.x & 3;
    int d = dq * 64 + dl;
    const float* row = fc_w + (long)d * 2048 + h * 256 + part * 64;
    float a = 0.f;
    #pragma unroll 8
    for (int i = 0; i < 64; i++) a += row[i] * ws_[part * 64 + i];
    a += __shfl_xor(a, 1);
    a += __shfl_xor(a, 2);
    if (part == 0) W[(long)x * 256 + d] = f2bf(a);
    if (threadIdx.x == 0 && dq == 0) {
        float cb = 0.f;
        const float* fb = fc_b + h * 256;
        for (int i = 0; i < 256; i++) cb += fb[i] * ws_[i];
        C[x] = cb + (kind ? k_b[0] : q_b[0]);
    }
}

// ---- q/k via MFMA: [8192 rows] x [16 eff cols], K=256; outputs *log2(e) ----
__global__ __launch_bounds__(256)
void k_qkm(const u16* __restrict__ featsB, const u16* __restrict__ Wb,
           const float* __restrict__ C,
           float* __restrict__ qo, float* __restrict__ ko) {
    int tid = threadIdx.x;
    int wave = tid >> 6, lane = tid & 63;
    int q = lane >> 4, n16 = lane & 15;
    int rowBase = blockIdx.x * 64 + wave * 16;
    const u16* arow = featsB + (long)(rowBase + n16) * 256 + q * 8;
    const u16* brow = Wb + n16 * 256 + q * 8;
    floatx4 acc = {};
    #pragma unroll
    for (int k0 = 0; k0 < 256; k0 += 32) {
        short8 af = *(const short8*)&arow[k0];
        short8 bf = *(const short8*)&brow[k0];
        acc = __builtin_amdgcn_mfma_f32_16x16x32_bf16(af, bf, acc, 0, 0, 0);
    }
    float cc = C[n16];
    #pragma unroll
    for (int r = 0; r < 4; r++) {
        int gr = rowBase + q * 4 + r;
        int b = gr >> 10, nn = gr & 1023;
        float v = (acc[r] + cc) * LOG2E;          // pre-scale for exp2 in k_attn
        if (n16 < 8) qo[((b * 8 + n16) << 10) + nn] = v;
        else         ko[((b * 8 + (n16 - 8)) << 10) + nn] = v;
    }
}

// ---------------- G1: fpjT2 = fc_w^T @ feats^T (k-grouped V layout) ----------
// 128x128 tile, BK=32, VGPR staging, padded LDS (stride 40, conflict-free).
// Store: V2[bh][n>>3][d][n&7] -- the k-grouped layout k_attn's DMA consumes.
__global__ __launch_bounds__(256, 2)
void k_g1(const u16* __restrict__ A, const u16* __restrict__ Bt,
          const float* __restrict__ bias, u16* __restrict__ V2) {
    __shared__ u16 As[128 * 40];
    __shared__ u16 Bs[128 * 40];
    int rowBase = blockIdx.y * 128;   // hd
    int colBase = blockIdx.x * 128;   // global n
    int tid  = threadIdx.x;
    int wave = tid >> 6, lane = tid & 63;
    int wr = wave >> 1, wc = wave & 1;
    int q  = lane >> 4, n16 = lane & 15;

    floatx4 acc[4][4] = {};
    int sm = tid >> 2;
    int sk = (tid & 3) * 8;

    for (int k0 = 0; k0 < 256; k0 += 32) {
        int4 a0 = *(const int4*)&A[(long)(rowBase + sm) * 256 + k0 + sk];
        int4 a1 = *(const int4*)&A[(long)(rowBase + sm + 64) * 256 + k0 + sk];
        int4 b0 = *(const int4*)&Bt[(long)(colBase + sm) * 256 + k0 + sk];
        int4 b1 = *(const int4*)&Bt[(long)(colBase + sm + 64) * 256 + k0 + sk];
        __syncthreads();
        *(int4*)&As[sm * 40 + sk]        = a0;
        *(int4*)&As[(sm + 64) * 40 + sk] = a1;
        *(int4*)&Bs[sm * 40 + sk]        = b0;
        *(int4*)&Bs[(sm + 64) * 40 + sk] = b1;
        __syncthreads();
        short8 af[4], bfr[4];
        #pragma unroll
        for (int i = 0; i < 4; i++)
            af[i] = *(short8*)&As[(wr * 64 + i * 16 + n16) * 40 + q * 8];
        #pragma unroll
        for (int i = 0; i < 4; i++)
            bfr[i] = *(short8*)&Bs[(wc * 64 + i * 16 + n16) * 40 + q * 8];
        #pragma unroll
        for (int mi = 0; mi < 4; mi++)
            #pragma unroll
            for (int ni = 0; ni < 4; ni++)
                acc[mi][ni] = __builtin_amdgcn_mfma_f32_16x16x32_bf16(
                    af[mi], bfr[ni], acc[mi][ni], 0, 0, 0);
    }

    #pragma unroll
    for (int mi = 0; mi < 4; mi++) {
        #pragma unroll
        for (int r = 0; r < 4; r++) {
            int grow = rowBase + wr * 64 + mi * 16 + q * 4 + r;
            int h = grow >> 8, d = grow & 255;
            float bv = bias[grow];
            #pragma unroll
            for (int ni = 0; ni < 4; ni++) {
                int gcol = colBase + wc * 64 + ni * 16 + n16;
                int b = gcol >> 10, nn = gcol & 1023;
                V2[(((long)(b * 8 + h)) << 18) + (nn >> 3) * 2048 + d * 8 + (nn & 7)]
                    = f2bf(acc[mi][ni][r] + bv);
            }
        }
    }
}

// -------- fused attention v5: chunk-major Bs (conflict-free), exp2 --------
// grid dim3(64, 8): x = bh (XCD locality), y = i-tile. V read from k-grouped
// fpjT2 via dense chunk-major DMA; bfr reads hit distinct banks per 8-lane
// phase group (round-6's 4.19M LDS conflicts came from the stride-32 row-major
// Bs). Output to k-grouped outh2 for k_g3's DMA.
__global__ __launch_bounds__(256)
__attribute__((amdgpu_waves_per_eu(2)))
void k_attn(const u32* __restrict__ maskW, const float* __restrict__ qv,
            const float* __restrict__ kv, const u16* __restrict__ fpjT2,
            u16* __restrict__ outh2) {
    __shared__ u16 As[2][128 * 40];       // P-tiles 128 x 32, stride 40
    __shared__ u16 Bs[2][4 * 256 * 8];    // V tiles, [chunk][d-row][8]
    __shared__ float qS[128], kS[1024], lsumS[256], rlS[128];

    int z = blockIdx.x;                   // bh  (XCD = z % 8)
    int b = z >> 3, h = z & 7;
    int i0 = blockIdx.y * 128;
    int tid = threadIdx.x;
    int wave = tid >> 6, lane = tid & 63;
    int wr = wave >> 1, wc = wave & 1;
    int q  = lane >> 4, n16 = lane & 15;

    *(float4*)&kS[tid * 4] = *(const float4*)&kv[(z << 10) + tid * 4];
    if (tid < 128) qS[tid] = qv[(z << 10) + i0 + tid];

    floatx4 acc[4][8] = {};
    int ar = tid >> 1;                    // P row (0..127)
    int jq = (tid & 1) * 16;              // P j-offset within BK
    const u32* mrow = maskW + (((long)(b << 10) + i0 + ar) << 5);
    const u16* Vbase = fpjT2 + ((long)z << 18);
    float lsum = 0.f;

    auto dma_v = [&](int k0, int p) {
        #pragma unroll
        for (int c = 0; c < 4; c++)
            __builtin_amdgcn_global_load_lds(
                (gp_t)&Vbase[((k0 >> 3) + c) * 2048 + (wave * 64 + lane) * 8],
                (sp_t)&Bs[p][(c * 256 + wave * 64 + lane) * 8],
                16, 0, 0);
    };
    auto stage_p = [&](int k0, int p) {
        u32 mw = mrow[k0 >> 5] >> jq;     // 16 mask bits for this thread
        float qi = qS[ar];
        float lkk[16];
        *(float4*)&lkk[0]  = *(const float4*)&kS[k0 + jq + 0];
        *(float4*)&lkk[4]  = *(const float4*)&kS[k0 + jq + 4];
        *(float4*)&lkk[8]  = *(const float4*)&kS[k0 + jq + 8];
        *(float4*)&lkk[12] = *(const float4*)&kS[k0 + jq + 12];
        u32 pw[8];
        #pragma unroll
        for (int e2 = 0; e2 < 8; e2++) {
            float s0 = qi + lkk[2 * e2];
            s0 = s0 > 0.f ? s0 : 0.01f * s0;
            float p0 = ((mw >> (2 * e2)) & 1u) ? exp2f(s0) : 0.f;
            float s1 = qi + lkk[2 * e2 + 1];
            s1 = s1 > 0.f ? s1 : 0.01f * s1;
            float p1 = ((mw >> (2 * e2 + 1)) & 1u) ? exp2f(s1) : 0.f;
            u32 t0 = __float_as_uint(p0) & 0xFFFF0000u;   // bf16 truncation
            u32 t1 = __float_as_uint(p1) & 0xFFFF0000u;
            lsum += __uint_as_float(t0) + __uint_as_float(t1);
            pw[e2] = (t0 >> 16) | t1;
        }
        *(int4*)&As[p][ar * 40 + jq]     = *(int4*)&pw[0];
        *(int4*)&As[p][ar * 40 + jq + 8] = *(int4*)&pw[4];
    };

    __syncthreads();                      // qS/kS visible
    dma_v(0, 0);
    stage_p(0, 0);
    __syncthreads();                      // iter 0 staged (DMA drained here)

    for (int k0 = 0; k0 < 1024; k0 += 32) {
        int p = (k0 >> 5) & 1;
        short8 af[4], bfr[8];
        #pragma unroll
        for (int i = 0; i < 4; i++)
            af[i] = *(short8*)&As[p][(wr * 64 + i * 16 + n16) * 40 + q * 8];
        #pragma unroll
        for (int i = 0; i < 8; i++)
            bfr[i] = *(short8*)&Bs[p][(q * 256 + wc * 128 + i * 16 + n16) * 8];
        if (k0 + 32 < 1024) {
            dma_v(k0 + 32, p ^ 1);
            stage_p(k0 + 32, p ^ 1);
        }
        #pragma unroll
        for (int mi = 0; mi < 4; mi++)
            #pragma unroll
            for (int ni = 0; ni < 8; ni++)
                acc[mi][ni] = __builtin_amdgcn_mfma_f32_16x16x32_bf16(
                    af[mi], bfr[ni], acc[mi][ni], 0, 0, 0);
        __syncthreads();                  // next buffer staged + DMA drained
    }

    lsumS[tid] = lsum;
    __syncthreads();
    if (tid < 128) {
        float l = lsumS[2 * tid] + lsumS[2 * tid + 1];
        rlS[tid] = l > 0.f ? 1.f / l : 0.f;
    }
    __syncthreads();

    #pragma unroll
    for (int mi = 0; mi < 4; mi++) {
        #pragma unroll
        for (int r = 0; r < 4; r++) {
            int grow = wr * 64 + mi * 16 + q * 4 + r;
            float s = rlS[grow];
            long row = (long)(b * 1024 + i0 + grow);
            #pragma unroll
            for (int ni = 0; ni < 8; ni++) {
                int gcol = wc * 128 + ni * 16 + n16;
                outh2[((long)(h * 32 + (gcol >> 3)) << 16) + row * 8 + (gcol & 7)]
                    = f2bf(acc[mi][ni][r] * s);
            }
        }
    }
}

// -------- G3 v2: out = sigmoid(outh2 @ fpwT2 + b + feats), pipelined --------
// BM=64 x BN=64, BK=64, grid (128,4) (row-tile fastest -> col-siblings share
// XCD L2 for the A-tile). Chunk-major double-buffered DMA, ONE barrier/iter,
// conflict-free frag reads. Round-6 G3 was 1 block/CU, 2-barrier, 67 us.
__global__ __launch_bounds__(256)
void k_g3(const u16* __restrict__ A2,   // outh2 [256][8192][8]
          const u16* __restrict__ B2,   // fpwT2 [256][256][8]
          const float* __restrict__ bias,
          const float* __restrict__ resid,
          float* __restrict__ out) {
    __shared__ u16 As[2][8 * 64 * 8];
    __shared__ u16 Bs[2][8 * 64 * 8];
    int rowBase = blockIdx.x * 64;
    int colBase = blockIdx.y * 64;
    int tid = threadIdx.x, wave = tid >> 6, lane = tid & 63;
    int wr = wave >> 1, wc = wave & 1;
    int q = lane >> 4, n16 = lane & 15;
    floatx4 acc[2][2] = {};

    auto dma = [&](int k0, int p) {
        #pragma unroll
        for (int s = 0; s < 2; s++) {
            int c = wave + s * 4;
            long kg = (k0 >> 3) + c;
            __builtin_amdgcn_global_load_lds(
                (gp_t)&A2[kg * 65536 + (rowBase + lane) * 8],
                (sp_t)&As[p][c * 512 + lane * 8], 16, 0, 0);
            __builtin_amdgcn_global_load_lds(
                (gp_t)&B2[kg * 2048 + (colBase + lane) * 8],
                (sp_t)&Bs[p][c * 512 + lane * 8], 16, 0, 0);
        }
    };

    dma(0, 0);
    __syncthreads();
    for (int k0 = 0; k0 < 2048; k0 += 64) {
        int p = (k0 >> 6) & 1;
        short8 af[2][2], bfr[2][2];
        #pragma unroll
        for (int s = 0; s < 2; s++)
            #pragma unroll
            for (int i = 0; i < 2; i++) {
                af[s][i]  = *(short8*)&As[p][((s * 4 + q) * 64 + wr * 32 + i * 16 + n16) * 8];
                bfr[s][i] = *(short8*)&Bs[p][((s * 4 + q) * 64 + wc * 32 + i * 16 + n16) * 8];
            }
        if (k0 + 64 < 2048) dma(k0 + 64, p ^ 1);
        #pragma unroll
        for (int s = 0; s < 2; s++)
            #pragma unroll
            for (int mi = 0; mi < 2; mi++)
                #pragma unroll
                for (int ni = 0; ni < 2; ni++)
                    acc[mi][ni] = __builtin_amdgcn_mfma_f32_16x16x32_bf16(
                        af[s][mi], bfr[s][ni], acc[mi][ni], 0, 0, 0);
        __syncthreads();
    }

    #pragma unroll
    for (int mi = 0; mi < 2; mi++) {
        #pragma unroll
        for (int r = 0; r < 4; r++) {
            int grow = rowBase + wr * 32 + mi * 16 + q * 4 + r;
            #pragma unroll
            for (int ni = 0; ni < 2; ni++) {
                int gcol = colBase + wc * 32 + ni * 16 + n16;
                float v = acc[mi][ni][r] + bias[gcol] + resid[(long)grow * 256 + gcol];
                out[(long)grow * 256 + gcol] = 1.f / (1.f + __expf(-v));
            }
        }
    }
}

extern "C" void kernel_launch(void* const* d_in, const int* in_sizes, int n_in,
                              void* d_out, int out_size, void* d_ws, size_t ws_size,
                              hipStream_t stream) {
    const float* feats = (const float*)d_in[0];
    const float* adj   = (const float*)d_in[1];
    const float* fc_w  = (const float*)d_in[2];
    const float* fc_b  = (const float*)d_in[3];
    const float* q_w   = (const float*)d_in[4];
    const float* q_b   = (const float*)d_in[5];
    const float* k_w   = (const float*)d_in[6];
    const float* k_b   = (const float*)d_in[7];
    const float* fp_w  = (const float*)d_in[8];
    const float* fp_b  = (const float*)d_in[9];

    char* ws = (char*)d_ws;
    u16*   featsB = (u16*)ws;   ws += (size_t)2097152 * 2;   // [8192][256] bf16
    u16*   fcwT   = (u16*)ws;   ws += (size_t)524288 * 2;    // [2048][256] bf16
    u16*   fpwT2  = (u16*)ws;   ws += (size_t)524288 * 2;    // k-grouped fp_w
    u16*   fpjT2  = (u16*)ws;   ws += (size_t)16777216 * 2;  // V2 [bh][j>>3][d][j&7]
    float* qv     = (float*)ws; ws += (size_t)65536 * 4;     // [b,h,n] (*log2e)
    float* kv     = (float*)ws; ws += (size_t)65536 * 4;
    u16*   outh2  = (u16*)ws;   ws += (size_t)16777216 * 2;  // [k>>3][row][k&7]
    u64*   maskB  = (u64*)ws;   ws += (size_t)131072 * 8;    // adj bits, 1 MB
    u16*   Weff   = (u16*)ws;   ws += (size_t)4096 * 2;      // [16][256] bf16
    float* Ceff   = (float*)ws; ws += (size_t)16 * 4;        // per-head consts

    // prep
    k_prep<<<32768, 256, 0, stream>>>(feats, adj, featsB, maskB);
    k_transpose<<<dim3(32, 4), 256, 0, stream>>>(fc_w, fcwT, 256, 2048);
    k_t2<<<2048, 256, 0, stream>>>(fp_w, fpwT2);
    k_wqk<<<dim3(16, 4), 256, 0, stream>>>(fc_w, fc_b, q_w, q_b, k_w, k_b, Weff, Ceff);

    // q, k via MFMA (pre-scaled by log2 e)
    k_qkm<<<128, 256, 0, stream>>>(featsB, Weff, Ceff, qv, kv);

    // G1: fpjT2 (k-grouped V)
    k_g1<<<dim3(64, 16), 256, 0, stream>>>(fcwT, featsB, fc_b, fpjT2);

    // fused scores + P@V + 1/l scaling
    k_attn<<<dim3(64, 8), 256, 0, stream>>>((const u32*)maskB, qv, kv, fpjT2, outh2);

    // G3: pipelined, 512 blocks
    k_g3<<<dim3(128, 4), 256, 0, stream>>>(outh2, fpwT2, fp_b, feats, (float*)d_out);
}

// Round 8
// 205.719 us; speedup vs baseline: 1.4673x; 1.1335x over previous
//
#include <hip/hip_runtime.h>
#include <hip/hip_bf16.h>

typedef unsigned short u16;
typedef unsigned int u32;
typedef unsigned long long u64;
typedef __attribute__((ext_vector_type(8))) short short8;   // 8 bf16 = 4 VGPR (MFMA A/B frag)
typedef __attribute__((ext_vector_type(4))) float floatx4;  // MFMA C/D frag
typedef const __attribute__((address_space(1))) void* gp_t; // global ptr for DMA
typedef __attribute__((address_space(3))) void* sp_t;       // LDS ptr for DMA

static __device__ __forceinline__ u16 f2bf(float x) {
    __hip_bfloat16 h = __float2bfloat16(x);
    union { __hip_bfloat16 h; u16 u; } cv; cv.h = h; return cv.u;
}
static __device__ __forceinline__ float bf2f(u16 u) {
    union { u16 u; __hip_bfloat16 h; } cv; cv.u = u;
    return __bfloat162float(cv.h);
}

// ---- fused prep: mask+cvt | fc_w transpose | fp_w k-group | eff q/k weights ----
__global__ __launch_bounds__(256)
void k_prepall(const float* __restrict__ feats, const float* __restrict__ adj,
               const float* __restrict__ fc_w, const float* __restrict__ fc_b,
               const float* __restrict__ q_w, const float* __restrict__ q_b,
               const float* __restrict__ k_w, const float* __restrict__ k_b,
               const float* __restrict__ fp_w,
               u16* __restrict__ featsB, u64* __restrict__ m,
               u16* __restrict__ fcwT, u16* __restrict__ fpwT2,
               u16* __restrict__ W, float* __restrict__ C) {
    __shared__ float shbuf[64 * 65];
    int id = blockIdx.x, tid = threadIdx.x;
    if (id < 32768) {                       // adj bitmask (+ feats cvt on first 2048)
        long i = (long)id * 256 + tid;
        float v = adj[i];
        u64 bm = __ballot(v > 0.f);
        if ((tid & 63) == 0) m[i >> 6] = bm;
        if (id < 2048) {
            int j = (id * 256 + tid) * 4;
            float4 f = *(const float4*)&feats[j];
            featsB[j + 0] = f2bf(f.x); featsB[j + 1] = f2bf(f.y);
            featsB[j + 2] = f2bf(f.z); featsB[j + 3] = f2bf(f.w);
        }
    } else if (id < 32896) {                // fc_w [256][2048] -> fcwT [2048][256]
        int t = id - 32768, bx = t & 31, by = t >> 5;
        float (*tt)[65] = (float(*)[65])shbuf;
        int c = tid & 63, r0 = tid >> 6;
        for (int rr = r0; rr < 64; rr += 4)
            tt[rr][c] = fc_w[(long)(by * 64 + rr) * 2048 + bx * 64 + c];
        __syncthreads();
        for (int rr = r0; rr < 64; rr += 4)
            fcwT[(long)(bx * 64 + rr) * 256 + by * 64 + c] = f2bf(tt[c][rr]);
    } else if (id < 34944) {                // fp_w -> k-grouped fpwT2
        int k = id - 32896;
        float v = fp_w[(long)k * 256 + tid];
        fpwT2[((long)(k >> 3)) * 2048 + tid * 8 + (k & 7)] = f2bf(v);
    } else {                                // effective q/k weights
        int t = id - 34944, x = t & 15, dq = t >> 4;
        int h = x & 7, kind = x >> 3;
        const float* w = kind ? k_w : q_w;
        float* ws_ = shbuf;
        ws_[tid] = w[tid];
        __syncthreads();
        int dl = tid >> 2, part = tid & 3;
        int d = dq * 64 + dl;
        const float* row = fc_w + (long)d * 2048 + h * 256 + part * 64;
        float a = 0.f;
        #pragma unroll 8
        for (int i = 0; i < 64; i++) a += row[i] * ws_[part * 64 + i];
        a += __shfl_xor(a, 1);
        a += __shfl_xor(a, 2);
        if (part == 0) W[(long)x * 256 + d] = f2bf(a);
        if (tid == 0 && dq == 0) {
            float cb = 0.f;
            const float* fb = fc_b + h * 256;
            for (int i = 0; i < 256; i++) cb += fb[i] * ws_[i];
            C[x] = cb + (kind ? k_b[0] : q_b[0]);
        }
    }
}

// ---- G1 (fpjT2 = fc_w^T @ feats^T, k-grouped V) + fused q/k MFMA blocks ----
__global__ __launch_bounds__(256, 2)
void k_g1qk(const u16* __restrict__ A, const u16* __restrict__ Bt,
            const float* __restrict__ bias, u16* __restrict__ V2,
            const u16* __restrict__ Wb, const float* __restrict__ C,
            float* __restrict__ qo, float* __restrict__ ko) {
    __shared__ u16 As[128 * 40];
    __shared__ u16 Bs[128 * 40];
    int tid  = threadIdx.x;
    int wave = tid >> 6, lane = tid & 63;
    int q  = lane >> 4, n16 = lane & 15;

    if (blockIdx.y >= 16) {                 // ---- q/k projection part ----
        int blk = (blockIdx.y - 16) * 64 + blockIdx.x;   // 0..127
        int rowBase = blk * 64 + wave * 16;
        const u16* arow = Bt + (long)(rowBase + n16) * 256 + q * 8;   // featsB
        const u16* brow = Wb + n16 * 256 + q * 8;
        floatx4 acc = {};
        #pragma unroll
        for (int k0 = 0; k0 < 256; k0 += 32) {
            short8 af = *(const short8*)&arow[k0];
            short8 bf = *(const short8*)&brow[k0];
            acc = __builtin_amdgcn_mfma_f32_16x16x32_bf16(af, bf, acc, 0, 0, 0);
        }
        float cc = C[n16];
        #pragma unroll
        for (int r = 0; r < 4; r++) {
            int gr = rowBase + q * 4 + r;
            int b = gr >> 10, nn = gr & 1023;
            float v = acc[r] + cc;
            if (n16 < 8) qo[((b * 8 + n16) << 10) + nn] = v;
            else         ko[((b * 8 + (n16 - 8)) << 10) + nn] = v;
        }
        return;
    }

    int rowBase = blockIdx.y * 128;   // hd
    int colBase = blockIdx.x * 128;   // global n
    int wr = wave >> 1, wc = wave & 1;
    floatx4 acc[4][4] = {};
    int sm = tid >> 2;
    int sk = (tid & 3) * 8;

    for (int k0 = 0; k0 < 256; k0 += 32) {
        int4 a0 = *(const int4*)&A[(long)(rowBase + sm) * 256 + k0 + sk];
        int4 a1 = *(const int4*)&A[(long)(rowBase + sm + 64) * 256 + k0 + sk];
        int4 b0 = *(const int4*)&Bt[(long)(colBase + sm) * 256 + k0 + sk];
        int4 b1 = *(const int4*)&Bt[(long)(colBase + sm + 64) * 256 + k0 + sk];
        __syncthreads();
        *(int4*)&As[sm * 40 + sk]        = a0;
        *(int4*)&As[(sm + 64) * 40 + sk] = a1;
        *(int4*)&Bs[sm * 40 + sk]        = b0;
        *(int4*)&Bs[(sm + 64) * 40 + sk] = b1;
        __syncthreads();
        short8 af[4], bfr[4];
        #pragma unroll
        for (int i = 0; i < 4; i++)
            af[i] = *(short8*)&As[(wr * 64 + i * 16 + n16) * 40 + q * 8];
        #pragma unroll
        for (int i = 0; i < 4; i++)
            bfr[i] = *(short8*)&Bs[(wc * 64 + i * 16 + n16) * 40 + q * 8];
        #pragma unroll
        for (int mi = 0; mi < 4; mi++)
            #pragma unroll
            for (int ni = 0; ni < 4; ni++)
                acc[mi][ni] = __builtin_amdgcn_mfma_f32_16x16x32_bf16(
                    af[mi], bfr[ni], acc[mi][ni], 0, 0, 0);
    }

    #pragma unroll
    for (int mi = 0; mi < 4; mi++) {
        #pragma unroll
        for (int r = 0; r < 4; r++) {
            int grow = rowBase + wr * 64 + mi * 16 + q * 4 + r;
            int h = grow >> 8, d = grow & 255;
            float bv = bias[grow];
            #pragma unroll
            for (int ni = 0; ni < 4; ni++) {
                int gcol = colBase + wc * 64 + ni * 16 + n16;
                int b = gcol >> 10, nn = gcol & 1023;
                V2[(((long)(b * 8 + h)) << 18) + (nn >> 3) * 2048 + d * 8 + (nn & 7)]
                    = f2bf(acc[mi][ni][r] + bv);
            }
        }
    }
}

// -------- fused attention v6: 512 threads (4 waves/SIMD latency hiding) --------
// 8 waves as 2x4 over the 128x256 tile; per-thread P work halves to 8 elem/iter.
// amdgpu_waves_per_eu(4) caps the VGPR budget at 128 (the 4-waves/SIMD class).
// __expf (v_mul+v_exp) -- round-7's exp2f was the precise OCML path.
// Pack via v_perm_b32 (1 inst/pair); lsum summed pre-truncation (err ~2^-9 rel).
__global__ __launch_bounds__(512)
__attribute__((amdgpu_waves_per_eu(4)))
void k_attn(const u32* __restrict__ maskW, const float* __restrict__ qv,
            const float* __restrict__ kv, const u16* __restrict__ fpjT2,
            u16* __restrict__ outh2) {
    __shared__ u16 As[2][128 * 40];       // P-tiles 128 x 32, stride 40
    __shared__ u16 Bs[2][4 * 256 * 8];    // V tiles, [chunk][d-row][8]
    __shared__ float qS[128], kS[1024], lsumS[512], rlS[128];

    int z = blockIdx.x;                   // bh  (XCD = z % 8)
    int b = z >> 3, h = z & 7;
    int i0 = blockIdx.y * 128;
    int tid = threadIdx.x;
    int wave = tid >> 6, lane = tid & 63;
    int wr = wave >> 2, wc = wave & 3;    // 2 x 4 wave grid
    int q  = lane >> 4, n16 = lane & 15;

    if (tid < 256) *(float4*)&kS[tid * 4] = *(const float4*)&kv[(z << 10) + tid * 4];
    if (tid >= 256 && tid < 384) qS[tid - 256] = qv[(z << 10) + i0 + (tid - 256)];

    floatx4 acc[4][4] = {};
    int ar = tid >> 2;                    // P row (0..127)
    int jq = (tid & 3) * 8;               // P j-offset within BK
    const u32* mrow = maskW + (((long)(b << 10) + i0 + ar) << 5);
    const u16* Vbase = fpjT2 + ((long)z << 18);
    float lsum = 0.f;

    auto dma_v = [&](int k0, int p) {
        #pragma unroll
        for (int t = 0; t < 2; t++) {
            int s = wave * 2 + t;         // 16 segments of 1 KB
            __builtin_amdgcn_global_load_lds(
                (gp_t)&Vbase[((k0 >> 3) + (s >> 2)) * 2048 + ((s & 3) * 64 + lane) * 8],
                (sp_t)&Bs[p][((s >> 2) * 256 + (s & 3) * 64 + lane) * 8],
                16, 0, 0);
        }
    };
    auto stage_p = [&](int k0, int p) {
        u32 mw = mrow[k0 >> 5] >> jq;     // 8 mask bits for this thread
        float qi = qS[ar];
        float4 kA = *(const float4*)&kS[k0 + jq];
        float4 kB = *(const float4*)&kS[k0 + jq + 4];
        float kk[8] = {kA.x, kA.y, kA.z, kA.w, kB.x, kB.y, kB.z, kB.w};
        u32 pw[4];
        #pragma unroll
        for (int e2 = 0; e2 < 4; e2++) {
            float s0 = qi + kk[2 * e2];
            s0 = fmaxf(s0, 0.01f * s0);               // leaky_relu
            float p0 = ((mw >> (2 * e2)) & 1u) ? __expf(s0) : 0.f;
            float s1 = qi + kk[2 * e2 + 1];
            s1 = fmaxf(s1, 0.01f * s1);
            float p1 = ((mw >> (2 * e2 + 1)) & 1u) ? __expf(s1) : 0.f;
            lsum += p0 + p1;
            pw[e2] = __builtin_amdgcn_perm(__float_as_uint(p1), __float_as_uint(p0),
                                           0x07060302);   // {bf16(p1),bf16(p0)}
        }
        *(int4*)&As[p][ar * 40 + jq] = *(int4*)&pw[0];
    };

    __syncthreads();                      // qS/kS visible
    dma_v(0, 0);
    stage_p(0, 0);
    __syncthreads();                      // iter 0 staged (DMA drained here)

    for (int k0 = 0; k0 < 1024; k0 += 32) {
        int p = (k0 >> 5) & 1;
        short8 af[4], bfr[4];
        #pragma unroll
        for (int i = 0; i < 4; i++)
            af[i] = *(short8*)&As[p][(wr * 64 + i * 16 + n16) * 40 + q * 8];
        #pragma unroll
        for (int i = 0; i < 4; i++)
            bfr[i] = *(short8*)&Bs[p][(q * 256 + wc * 64 + i * 16 + n16) * 8];
        if (k0 + 32 < 1024) {
            dma_v(k0 + 32, p ^ 1);
            stage_p(k0 + 32, p ^ 1);
        }
        #pragma unroll
        for (int mi = 0; mi < 4; mi++)
            #pragma unroll
            for (int ni = 0; ni < 4; ni++)
                acc[mi][ni] = __builtin_amdgcn_mfma_f32_16x16x32_bf16(
                    af[mi], bfr[ni], acc[mi][ni], 0, 0, 0);
        __syncthreads();                  // next buffer staged + DMA drained
    }

    lsumS[tid] = lsum;
    __syncthreads();
    if (tid < 128) {
        float l = lsumS[4 * tid] + lsumS[4 * tid + 1] +
                  lsumS[4 * tid + 2] + lsumS[4 * tid + 3];
        rlS[tid] = l > 0.f ? 1.f / l : 0.f;
    }
    __syncthreads();

    #pragma unroll
    for (int mi = 0; mi < 4; mi++) {
        #pragma unroll
        for (int r = 0; r < 4; r++) {
            int grow = wr * 64 + mi * 16 + q * 4 + r;
            float s = rlS[grow];
            long row = (long)(b * 1024 + i0 + grow);
            #pragma unroll
            for (int ni = 0; ni < 4; ni++) {
                int gcol = wc * 64 + ni * 16 + n16;
                outh2[((long)(h * 32 + (gcol >> 3)) << 16) + row * 8 + (gcol & 7)]
                    = f2bf(acc[mi][ni][r] * s);
            }
        }
    }
}

// -------- G3 v3: 64x32 tiles, grid (128,8) = 4 blocks/CU, x=row-tile so the
// 8 col-siblings share an XCD (A2 fetched from HBM once, L2-served 8x). --------
__global__ __launch_bounds__(256)
void k_g3(const u16* __restrict__ A2,   // outh2 [256][8192][8]
          const u16* __restrict__ B2,   // fpwT2 [256][256][8]
          const float* __restrict__ bias,
          const float* __restrict__ resid,
          float* __restrict__ out) {
    __shared__ u16 As[2][8 * 64 * 8];   // 8 KB / buf
    __shared__ u16 Bs[2][8 * 32 * 8];   // 4 KB / buf
    int rowBase = blockIdx.x * 64;
    int colBase = blockIdx.y * 32;
    int tid = threadIdx.x, wave = tid >> 6, lane = tid & 63;
    int q = lane >> 4, n16 = lane & 15;
    floatx4 acc[2] = {};

    auto dma = [&](int k0, int p) {
        int kc = k0 >> 3;
        #pragma unroll
        for (int t = 0; t < 2; t++) {
            int c = wave + t * 4;
            __builtin_amdgcn_global_load_lds(
                (gp_t)&A2[(long)(kc + c) * 65536 + (rowBase + lane) * 8],
                (sp_t)&As[p][(c * 64 + lane) * 8], 16, 0, 0);
        }
        __builtin_amdgcn_global_load_lds(
            (gp_t)&B2[(long)(kc + wave * 2 + (lane >> 5)) * 2048
                      + (colBase + (lane & 31)) * 8],
            (sp_t)&Bs[p][(wave * 64 + lane) * 8], 16, 0, 0);
    };

    dma(0, 0);
    __syncthreads();
    for (int k0 = 0; k0 < 2048; k0 += 64) {
        int p = (k0 >> 6) & 1;
        short8 af[2], bfr[2][2];
        #pragma unroll
        for (int kf = 0; kf < 2; kf++) {
            af[kf] = *(short8*)&As[p][((kf * 4 + q) * 64 + wave * 16 + n16) * 8];
            #pragma unroll
            for (int nf = 0; nf < 2; nf++)
                bfr[kf][nf] = *(short8*)&Bs[p][((kf * 4 + q) * 32 + nf * 16 + n16) * 8];
        }
        if (k0 + 64 < 2048) dma(k0 + 64, p ^ 1);
        #pragma unroll
        for (int kf = 0; kf < 2; kf++)
            #pragma unroll
            for (int nf = 0; nf < 2; nf++)
                acc[nf] = __builtin_amdgcn_mfma_f32_16x16x32_bf16(
                    af[kf], bfr[kf][nf], acc[nf], 0, 0, 0);
        __syncthreads();
    }

    #pragma unroll
    for (int nf = 0; nf < 2; nf++) {
        #pragma unroll
        for (int r = 0; r < 4; r++) {
            int grow = rowBase + wave * 16 + q * 4 + r;
            int gcol = colBase + nf * 16 + n16;
            float v = acc[nf][r] + bias[gcol] + resid[(long)grow * 256 + gcol];
            out[(long)grow * 256 + gcol] = 1.f / (1.f + __expf(-v));
        }
    }
}

extern "C" void kernel_launch(void* const* d_in, const int* in_sizes, int n_in,
                              void* d_out, int out_size, void* d_ws, size_t ws_size,
                              hipStream_t stream) {
    const float* feats = (const float*)d_in[0];
    const float* adj   = (const float*)d_in[1];
    const float* fc_w  = (const float*)d_in[2];
    const float* fc_b  = (const float*)d_in[3];
    const float* q_w   = (const float*)d_in[4];
    const float* q_b   = (const float*)d_in[5];
    const float* k_w   = (const float*)d_in[6];
    const float* k_b   = (const float*)d_in[7];
    const float* fp_w  = (const float*)d_in[8];
    const float* fp_b  = (const float*)d_in[9];

    char* ws = (char*)d_ws;
    u16*   featsB = (u16*)ws;   ws += (size_t)2097152 * 2;   // [8192][256] bf16
    u16*   fcwT   = (u16*)ws;   ws += (size_t)524288 * 2;    // [2048][256] bf16
    u16*   fpwT2  = (u16*)ws;   ws += (size_t)524288 * 2;    // k-grouped fp_w
    u16*   fpjT2  = (u16*)ws;   ws += (size_t)16777216 * 2;  // V2 [bh][j>>3][d][j&7]
    float* qv     = (float*)ws; ws += (size_t)65536 * 4;     // [b,h,n]
    float* kv     = (float*)ws; ws += (size_t)65536 * 4;
    u16*   outh2  = (u16*)ws;   ws += (size_t)16777216 * 2;  // [k>>3][row][k&7]
    u64*   maskB  = (u64*)ws;   ws += (size_t)131072 * 8;    // adj bits, 1 MB
    u16*   Weff   = (u16*)ws;   ws += (size_t)4096 * 2;      // [16][256] bf16
    float* Ceff   = (float*)ws; ws += (size_t)16 * 4;        // per-head consts

    // all prep in one launch (small parts ride in the adj-read shadow)
    k_prepall<<<35008, 256, 0, stream>>>(feats, adj, fc_w, fc_b, q_w, q_b,
                                         k_w, k_b, fp_w,
                                         featsB, maskB, fcwT, fpwT2, Weff, Ceff);

    // G1 (k-grouped V) + q/k projection fused in one launch
    k_g1qk<<<dim3(64, 18), 256, 0, stream>>>(fcwT, featsB, fc_b, fpjT2,
                                             Weff, Ceff, qv, kv);

    // fused scores + P@V + 1/l scaling
    k_attn<<<dim3(64, 8), 512, 0, stream>>>((const u32*)maskB, qv, kv, fpjT2, outh2);

    // G3: sigmoid(outh2 @ fp_w + fp_b + feats)
    k_g3<<<dim3(128, 8), 256, 0, stream>>>(outh2, fpwT2, fp_b, feats, (float*)d_out);
}

// Round 9
// 195.021 us; speedup vs baseline: 1.5478x; 1.0549x over previous
//
#include <hip/hip_runtime.h>
#include <hip/hip_bf16.h>

typedef unsigned short u16;
typedef unsigned int u32;
typedef unsigned long long u64;
typedef __attribute__((ext_vector_type(8))) short short8;   // 8 bf16 = 4 VGPR (MFMA A/B frag)
typedef __attribute__((ext_vector_type(4))) float floatx4;  // MFMA C/D frag
typedef const __attribute__((address_space(1))) void* gp_t; // global ptr for DMA
typedef __attribute__((address_space(3))) void* sp_t;       // LDS ptr for DMA

static __device__ __forceinline__ u16 f2bf(float x) {
    __hip_bfloat16 h = __float2bfloat16(x);
    union { __hip_bfloat16 h; u16 u; } cv; cv.h = h; return cv.u;
}

// ---- fused prep (3392 blocks): adj bitmask | feats k-group | fc_w k-group
// ---- | fp_w k-group | effective q/k weights.  All stores 16 B except mask.
__global__ __launch_bounds__(256)
void k_prepall(const float* __restrict__ feats, const float* __restrict__ adj,
               const float* __restrict__ fc_w, const float* __restrict__ fc_b,
               const float* __restrict__ q_w, const float* __restrict__ q_b,
               const float* __restrict__ k_w, const float* __restrict__ k_b,
               const float* __restrict__ fp_w,
               u16* __restrict__ feats2, u16* __restrict__ maskH,
               u16* __restrict__ fcw2, u16* __restrict__ fpw2,
               u16* __restrict__ W, float* __restrict__ C) {
    __shared__ float shbuf[64 * 65];
    int id = blockIdx.x, t = threadIdx.x;
    if (id < 2048) {                        // adj -> bits, 16 elems/thread
        long g = (long)id * 256 + t;
        const float4* ap = (const float4*)adj + g * 4;
        u32 mm = 0;
        #pragma unroll
        for (int w = 0; w < 4; w++) {
            float4 f = ap[w];
            mm |= (f.x > 0.f ? 1u : 0u) << (4 * w);
            mm |= (f.y > 0.f ? 1u : 0u) << (4 * w + 1);
            mm |= (f.z > 0.f ? 1u : 0u) << (4 * w + 2);
            mm |= (f.w > 0.f ? 1u : 0u) << (4 * w + 3);
        }
        maskH[g] = (u16)mm;
    } else if (id < 3072) {                 // feats -> feats2[d>>3][n][d&7]
        int n = (id - 2048) * 8 + (t >> 5), c = t & 31;
        const float* src = feats + (long)n * 256 + c * 8;
        float4 f0 = *(const float4*)src, f1 = *(const float4*)(src + 4);
        u16 tmp[8] = {f2bf(f0.x), f2bf(f0.y), f2bf(f0.z), f2bf(f0.w),
                      f2bf(f1.x), f2bf(f1.y), f2bf(f1.z), f2bf(f1.w)};
        *(int4*)&feats2[(long)c * 65536 + n * 8] = *(int4*)tmp;
    } else if (id < 3200) {                 // fc_w[256k][2048hd] -> fcw2[k>>3][hd][k&7]
        int b = id - 3072, bx = b & 31, by = b >> 5;
        float (*tt)[65] = (float(*)[65])shbuf;
        int c = t & 63, r0 = t >> 6;
        for (int rr = r0; rr < 64; rr += 4)
            tt[rr][c] = fc_w[(long)(by * 64 + rr) * 2048 + bx * 64 + c];
        __syncthreads();
        int hdl = t & 63;
        #pragma unroll
        for (int oo = 0; oo < 2; oo++) {
            int o = (t >> 6) + oo * 4;
            u16 tmp[8];
            #pragma unroll
            for (int e = 0; e < 8; e++) tmp[e] = f2bf(tt[o * 8 + e][hdl]);
            *(int4*)&fcw2[(long)(by * 8 + o) * 16384 + (bx * 64 + hdl) * 8] = *(int4*)tmp;
        }
    } else if (id < 3328) {                 // fp_w[2048k][256c] -> fpw2[k>>3][c][k&7]
        int b = id - 3200, bx = b & 3, by = b >> 2;
        float (*tt)[65] = (float(*)[65])shbuf;
        int c = t & 63, r0 = t >> 6;
        for (int rr = r0; rr < 64; rr += 4)
            tt[rr][c] = fp_w[(long)(by * 64 + rr) * 256 + bx * 64 + c];
        __syncthreads();
        int cl = t & 63;
        #pragma unroll
        for (int oo = 0; oo < 2; oo++) {
            int o = (t >> 6) + oo * 4;
            u16 tmp[8];
            #pragma unroll
            for (int e = 0; e < 8; e++) tmp[e] = f2bf(tt[o * 8 + e][cl]);
            *(int4*)&fpw2[(long)(by * 8 + o) * 2048 + (bx * 64 + cl) * 8] = *(int4*)tmp;
        }
    } else {                                // effective q/k weights
        int t2 = id - 3328, x = t2 & 15, dq = t2 >> 4;
        int h = x & 7, kind = x >> 3;
        const float* w = kind ? k_w : q_w;
        float* ws_ = shbuf;
        ws_[t] = w[t];
        __syncthreads();
        int dl = t >> 2, part = t & 3;
        int d = dq * 64 + dl;
        const float* row = fc_w + (long)d * 2048 + h * 256 + part * 64;
        float a = 0.f;
        #pragma unroll 8
        for (int i = 0; i < 64; i++) a += row[i] * ws_[part * 64 + i];
        a += __shfl_xor(a, 1);
        a += __shfl_xor(a, 2);
        if (part == 0) W[(long)x * 256 + d] = f2bf(a);
        if (t == 0 && dq == 0) {
            float cb = 0.f;
            const float* fb = fc_b + h * 256;
            for (int i = 0; i < 256; i++) cb += fb[i] * ws_[i];
            C[x] = cb + (kind ? k_b[0] : q_b[0]);
        }
    }
}

// ---- G1 (single-barrier DMA pipeline) + fused q/k MFMA blocks ----
// G1: C[hd][n] = fcw2^T-ish @ feats2, BM=BN=128, BK=32 (4 chunks), 8 iters,
// double-buffered chunk-major LDS (conflict-free frag reads), 32 KB LDS.
__global__ __launch_bounds__(256)
void k_g1qk(const u16* __restrict__ fcw2, const u16* __restrict__ feats2,
            const float* __restrict__ bias, u16* __restrict__ V2,
            const u16* __restrict__ Wb, const float* __restrict__ C,
            float* __restrict__ qo, float* __restrict__ ko) {
    int tid = threadIdx.x, wave = tid >> 6, lane = tid & 63;
    int q = lane >> 4, n16 = lane & 15;

    if (blockIdx.y >= 16) {                 // ---- q/k projection part ----
        int blk = (blockIdx.y - 16) * 64 + blockIdx.x;   // 0..127
        int rowBase = blk * 64 + wave * 16;
        floatx4 acc = {};
        #pragma unroll
        for (int k0 = 0; k0 < 256; k0 += 32) {
            short8 af = *(const short8*)&feats2[(long)((k0 >> 3) + q) * 65536
                                                + (rowBase + n16) * 8];
            short8 bf = *(const short8*)&Wb[n16 * 256 + k0 + q * 8];
            acc = __builtin_amdgcn_mfma_f32_16x16x32_bf16(af, bf, acc, 0, 0, 0);
        }
        float cc = C[n16];
        #pragma unroll
        for (int r = 0; r < 4; r++) {
            int gr = rowBase + q * 4 + r;
            int b = gr >> 10, nn = gr & 1023;
            float v = acc[r] + cc;
            if (n16 < 8) qo[((b * 8 + n16) << 10) + nn] = v;
            else         ko[((b * 8 + (n16 - 8)) << 10) + nn] = v;
        }
        return;
    }

    __shared__ u16 As[2][4 * 128 * 8];      // 8 KB / buf
    __shared__ u16 Bs[2][4 * 128 * 8];
    int rowBase = blockIdx.y * 128;         // hd
    int colBase = blockIdx.x * 128;         // n
    int wr = wave >> 1, wc = wave & 1;
    floatx4 acc[4][4] = {};

    auto dma = [&](int k0, int p) {
        int kc = k0 >> 3;
        #pragma unroll
        for (int r = 0; r < 2; r++) {
            __builtin_amdgcn_global_load_lds(
                (gp_t)&fcw2[(long)(kc + wave) * 16384 + (rowBase + r * 64 + lane) * 8],
                (sp_t)&As[p][(wave * 128 + r * 64 + lane) * 8], 16, 0, 0);
            __builtin_amdgcn_global_load_lds(
                (gp_t)&feats2[(long)(kc + wave) * 65536 + (colBase + r * 64 + lane) * 8],
                (sp_t)&Bs[p][(wave * 128 + r * 64 + lane) * 8], 16, 0, 0);
        }
    };

    dma(0, 0);
    __syncthreads();
    for (int k0 = 0; k0 < 256; k0 += 32) {
        int p = (k0 >> 5) & 1;
        short8 af[4], bfr[4];
        #pragma unroll
        for (int i = 0; i < 4; i++)
            af[i] = *(short8*)&As[p][(q * 128 + wr * 64 + i * 16 + n16) * 8];
        #pragma unroll
        for (int i = 0; i < 4; i++)
            bfr[i] = *(short8*)&Bs[p][(q * 128 + wc * 64 + i * 16 + n16) * 8];
        if (k0 + 32 < 256) dma(k0 + 32, p ^ 1);
        #pragma unroll
        for (int mi = 0; mi < 4; mi++)
            #pragma unroll
            for (int ni = 0; ni < 4; ni++)
                acc[mi][ni] = __builtin_amdgcn_mfma_f32_16x16x32_bf16(
                    af[mi], bfr[ni], acc[mi][ni], 0, 0, 0);
        __syncthreads();
    }

    #pragma unroll
    for (int mi = 0; mi < 4; mi++) {
        #pragma unroll
        for (int r = 0; r < 4; r++) {
            int grow = rowBase + wr * 64 + mi * 16 + q * 4 + r;
            int h = grow >> 8, d = grow & 255;
            float bv = bias[grow];
            #pragma unroll
            for (int ni = 0; ni < 4; ni++) {
                int gcol = colBase + wc * 64 + ni * 16 + n16;
                int b = gcol >> 10, nn = gcol & 1023;
                V2[(((long)(b * 8 + h)) << 18) + (nn >> 3) * 2048 + d * 8 + (nn & 7)]
                    = f2bf(acc[mi][ni][r] + bv);
            }
        }
    }
}

// -------- fused attention v7: mask + k prefetch off the critical chain --------
__global__ __launch_bounds__(512)
__attribute__((amdgpu_waves_per_eu(4)))
void k_attn(const u32* __restrict__ maskW, const float* __restrict__ qv,
            const float* __restrict__ kv, const u16* __restrict__ fpjT2,
            u16* __restrict__ outh2) {
    __shared__ u16 As[2][128 * 40];       // P-tiles 128 x 32, stride 40
    __shared__ u16 Bs[2][4 * 256 * 8];    // V tiles, [chunk][d-row][8]
    __shared__ float qS[128], kS[1024], lsumS[512], rlS[128];

    int z = blockIdx.x;                   // bh  (XCD = z % 8)
    int b = z >> 3, h = z & 7;
    int i0 = blockIdx.y * 128;
    int tid = threadIdx.x;
    int wave = tid >> 6, lane = tid & 63;
    int wr = wave >> 2, wc = wave & 3;    // 2 x 4 wave grid
    int q  = lane >> 4, n16 = lane & 15;

    if (tid < 256) *(float4*)&kS[tid * 4] = *(const float4*)&kv[(z << 10) + tid * 4];
    if (tid >= 256 && tid < 384) qS[tid - 256] = qv[(z << 10) + i0 + (tid - 256)];

    floatx4 acc[4][4] = {};
    int ar = tid >> 2;                    // P row (0..127)
    int jq = (tid & 3) * 8;               // P j-offset within BK
    const u32* mrow = maskW + (((long)(b << 10) + i0 + ar) << 5);
    const u16* Vbase = fpjT2 + ((long)z << 18);
    float lsum = 0.f;

    auto dma_v = [&](int k0, int p) {
        #pragma unroll
        for (int t = 0; t < 2; t++) {
            int s = wave * 2 + t;         // 16 segments of 1 KB
            __builtin_amdgcn_global_load_lds(
                (gp_t)&Vbase[((k0 >> 3) + (s >> 2)) * 2048 + ((s & 3) * 64 + lane) * 8],
                (sp_t)&Bs[p][((s >> 2) * 256 + (s & 3) * 64 + lane) * 8],
                16, 0, 0);
        }
    };

    __syncthreads();                      // qS/kS visible
    float qi = qS[ar];

    auto stage_p = [&](int p, u32 mw, float4 kA, float4 kB) {
        float kk[8] = {kA.x, kA.y, kA.z, kA.w, kB.x, kB.y, kB.z, kB.w};
        u32 pw[4];
        #pragma unroll
        for (int e2 = 0; e2 < 4; e2++) {
            float s0 = qi + kk[2 * e2];
            s0 = fmaxf(s0, 0.01f * s0);               // leaky_relu
            float p0 = ((mw >> (2 * e2)) & 1u) ? __expf(s0) : 0.f;
            float s1 = qi + kk[2 * e2 + 1];
            s1 = fmaxf(s1, 0.01f * s1);
            float p1 = ((mw >> (2 * e2 + 1)) & 1u) ? __expf(s1) : 0.f;
            lsum += p0 + p1;
            pw[e2] = __builtin_amdgcn_perm(__float_as_uint(p1), __float_as_uint(p0),
                                           0x07060302);   // {bf16(p1),bf16(p0)}
        }
        *(int4*)&As[p][ar * 40 + jq] = *(int4*)&pw[0];
    };

    {
        u32 mw0 = mrow[0] >> jq;
        float4 kA0 = *(const float4*)&kS[jq];
        float4 kB0 = *(const float4*)&kS[jq + 4];
        dma_v(0, 0);
        stage_p(0, mw0, kA0, kB0);
    }
    __syncthreads();                      // iter 0 staged (DMA drained here)

    for (int k0 = 0; k0 < 1024; k0 += 32) {
        int p = (k0 >> 5) & 1;
        int kn = (k0 + 32 < 1024) ? k0 + 32 : 0;
        // prefetch next iter's mask word + k values (issue before frag reads)
        u32 mw = mrow[kn >> 5] >> jq;
        float4 kA = *(const float4*)&kS[kn + jq];
        float4 kB = *(const float4*)&kS[kn + jq + 4];
        short8 af[4], bfr[4];
        #pragma unroll
        for (int i = 0; i < 4; i++)
            af[i] = *(short8*)&As[p][(wr * 64 + i * 16 + n16) * 40 + q * 8];
        #pragma unroll
        for (int i = 0; i < 4; i++)
            bfr[i] = *(short8*)&Bs[p][(q * 256 + wc * 64 + i * 16 + n16) * 8];
        if (k0 + 32 < 1024) {
            dma_v(k0 + 32, p ^ 1);
            stage_p(p ^ 1, mw, kA, kB);
        }
        #pragma unroll
        for (int mi = 0; mi < 4; mi++)
            #pragma unroll
            for (int ni = 0; ni < 4; ni++)
                acc[mi][ni] = __builtin_amdgcn_mfma_f32_16x16x32_bf16(
                    af[mi], bfr[ni], acc[mi][ni], 0, 0, 0);
        __syncthreads();                  // next buffer staged + DMA drained
    }

    lsumS[tid] = lsum;
    __syncthreads();
    if (tid < 128) {
        float l = lsumS[4 * tid] + lsumS[4 * tid + 1] +
                  lsumS[4 * tid + 2] + lsumS[4 * tid + 3];
        rlS[tid] = l > 0.f ? 1.f / l : 0.f;
    }
    __syncthreads();

    #pragma unroll
    for (int mi = 0; mi < 4; mi++) {
        #pragma unroll
        for (int r = 0; r < 4; r++) {
            int grow = wr * 64 + mi * 16 + q * 4 + r;
            float s = rlS[grow];
            long row = (long)(b * 1024 + i0 + grow);
            #pragma unroll
            for (int ni = 0; ni < 4; ni++) {
                int gcol = wc * 64 + ni * 16 + n16;
                outh2[((long)(h * 32 + (gcol >> 3)) << 16) + row * 8 + (gcol & 7)]
                    = f2bf(acc[mi][ni][r] * s);
            }
        }
    }
}

// -------- G3 v4: 64x64 tiles, BK=64 (16 iters), 1 barrier/iter, 512 blocks ----
__global__ __launch_bounds__(256)
void k_g3(const u16* __restrict__ A2,   // outh2 [256][8192][8]
          const u16* __restrict__ B2,   // fpw2  [256][256][8]
          const float* __restrict__ bias,
          const float* __restrict__ resid,
          float* __restrict__ out) {
    __shared__ u16 As[2][8 * 64 * 8];   // 8 KB / buf
    __shared__ u16 Bs[2][8 * 64 * 8];
    int rowBase = blockIdx.x * 64;
    int colBase = blockIdx.y * 64;
    int tid = threadIdx.x, wave = tid >> 6, lane = tid & 63;
    int wr = wave >> 1, wc = wave & 1;
    int q = lane >> 4, n16 = lane & 15;
    floatx4 acc[2][2] = {};

    auto dma = [&](int k0, int p) {
        int kc = k0 >> 3;
        #pragma unroll
        for (int s = 0; s < 2; s++) {
            int c = wave + s * 4;
            __builtin_amdgcn_global_load_lds(
                (gp_t)&A2[(long)(kc + c) * 65536 + (rowBase + lane) * 8],
                (sp_t)&As[p][(c * 64 + lane) * 8], 16, 0, 0);
            __builtin_amdgcn_global_load_lds(
                (gp_t)&B2[(long)(kc + c) * 2048 + (colBase + lane) * 8],
                (sp_t)&Bs[p][(c * 64 + lane) * 8], 16, 0, 0);
        }
    };

    dma(0, 0);
    __syncthreads();
    for (int k0 = 0; k0 < 2048; k0 += 64) {
        int p = (k0 >> 6) & 1;
        short8 af[2][2], bfr[2][2];
        #pragma unroll
        for (int kf = 0; kf < 2; kf++)
            #pragma unroll
            for (int i = 0; i < 2; i++) {
                af[kf][i]  = *(short8*)&As[p][((kf * 4 + q) * 64 + wr * 32 + i * 16 + n16) * 8];
                bfr[kf][i] = *(short8*)&Bs[p][((kf * 4 + q) * 64 + wc * 32 + i * 16 + n16) * 8];
            }
        if (k0 + 64 < 2048) dma(k0 + 64, p ^ 1);
        #pragma unroll
        for (int kf = 0; kf < 2; kf++)
            #pragma unroll
            for (int mi = 0; mi < 2; mi++)
                #pragma unroll
                for (int ni = 0; ni < 2; ni++)
                    acc[mi][ni] = __builtin_amdgcn_mfma_f32_16x16x32_bf16(
                        af[kf][mi], bfr[kf][ni], acc[mi][ni], 0, 0, 0);
        __syncthreads();
    }

    #pragma unroll
    for (int mi = 0; mi < 2; mi++) {
        #pragma unroll
        for (int r = 0; r < 4; r++) {
            int grow = rowBase + wr * 32 + mi * 16 + q * 4 + r;
            #pragma unroll
            for (int ni = 0; ni < 2; ni++) {
                int gcol = colBase + wc * 32 + ni * 16 + n16;
                float v = acc[mi][ni][r] + bias[gcol] + resid[(long)grow * 256 + gcol];
                out[(long)grow * 256 + gcol] = 1.f / (1.f + __expf(-v));
            }
        }
    }
}

extern "C" void kernel_launch(void* const* d_in, const int* in_sizes, int n_in,
                              void* d_out, int out_size, void* d_ws, size_t ws_size,
                              hipStream_t stream) {
    const float* feats = (const float*)d_in[0];
    const float* adj   = (const float*)d_in[1];
    const float* fc_w  = (const float*)d_in[2];
    const float* fc_b  = (const float*)d_in[3];
    const float* q_w   = (const float*)d_in[4];
    const float* q_b   = (const float*)d_in[5];
    const float* k_w   = (const float*)d_in[6];
    const float* k_b   = (const float*)d_in[7];
    const float* fp_w  = (const float*)d_in[8];
    const float* fp_b  = (const float*)d_in[9];

    char* ws = (char*)d_ws;
    u16*   feats2 = (u16*)ws;   ws += (size_t)2097152 * 2;   // [d>>3][n][d&7]
    u16*   fcw2   = (u16*)ws;   ws += (size_t)524288 * 2;    // [k>>3][hd][k&7]
    u16*   fpw2   = (u16*)ws;   ws += (size_t)524288 * 2;    // [k>>3][col][k&7]
    u16*   fpjT2  = (u16*)ws;   ws += (size_t)16777216 * 2;  // V2 [bh][n>>3][d][n&7]
    float* qv     = (float*)ws; ws += (size_t)65536 * 4;     // [b,h,n]
    float* kv     = (float*)ws; ws += (size_t)65536 * 4;
    u16*   outh2  = (u16*)ws;   ws += (size_t)16777216 * 2;  // [k>>3][row][k&7]
    u64*   maskB  = (u64*)ws;   ws += (size_t)131072 * 8;    // adj bits, 1 MB
    u16*   Weff   = (u16*)ws;   ws += (size_t)4096 * 2;      // [16][256] bf16
    float* Ceff   = (float*)ws; ws += (size_t)16 * 4;        // per-head consts

    // all prep in one lean launch (3392 blocks vs round-8's 35008)
    k_prepall<<<3392, 256, 0, stream>>>(feats, adj, fc_w, fc_b, q_w, q_b,
                                        k_w, k_b, fp_w,
                                        feats2, (u16*)maskB, fcw2, fpw2, Weff, Ceff);

    // G1 (k-grouped V, 1-barrier pipeline) + q/k projection
    k_g1qk<<<dim3(64, 18), 256, 0, stream>>>(fcw2, feats2, fc_b, fpjT2,
                                             Weff, Ceff, qv, kv);

    // fused scores + P@V + 1/l scaling
    k_attn<<<dim3(64, 8), 512, 0, stream>>>((const u32*)maskB, qv, kv, fpjT2, outh2);

    // G3: sigmoid(outh2 @ fp_w + fp_b + feats)
    k_g3<<<dim3(128, 4), 256, 0, stream>>>(outh2, fpw2, fp_b, feats, (float*)d_out);
}

// Round 11
// 186.334 us; speedup vs baseline: 1.6200x; 1.0466x over previous
//
#include <hip/hip_runtime.h>
#include <hip/hip_bf16.h>

typedef unsigned short u16;
typedef unsigned int u32;
typedef unsigned long long u64;
typedef __attribute__((ext_vector_type(8))) short short8;   // 8 bf16 = 4 VGPR (MFMA A/B frag)
typedef __attribute__((ext_vector_type(4))) float floatx4;  // MFMA C/D frag
typedef const __attribute__((address_space(1))) void* gp_t; // global ptr for DMA
typedef __attribute__((address_space(3))) void* sp_t;       // LDS ptr for DMA

#define LOG2E 1.44269504088896f

static __device__ __forceinline__ float exp2_raw(float x) {
    float r; asm("v_exp_f32 %0, %1" : "=v"(r) : "v"(x)); return r;
}

static __device__ __forceinline__ u16 f2bf(float x) {
    __hip_bfloat16 h = __float2bfloat16(x);
    union { __hip_bfloat16 h; u16 u; } cv; cv.h = h; return cv.u;
}

// ---- fused prep (3392 blocks): adj bitmask | feats k-group | fc_w k-group
// ---- | fp_w k-group | effective q/k weights.
__global__ __launch_bounds__(256)
void k_prepall(const float* __restrict__ feats, const float* __restrict__ adj,
               const float* __restrict__ fc_w, const float* __restrict__ fc_b,
               const float* __restrict__ q_w, const float* __restrict__ q_b,
               const float* __restrict__ k_w, const float* __restrict__ k_b,
               const float* __restrict__ fp_w,
               u16* __restrict__ feats2, u16* __restrict__ maskH,
               u16* __restrict__ fcw2, u16* __restrict__ fpw2,
               u16* __restrict__ W, float* __restrict__ C) {
    __shared__ float shbuf[64 * 65];
    int id = blockIdx.x, t = threadIdx.x;
    if (id < 2048) {                        // adj -> bits, 16 elems/thread
        long g = (long)id * 256 + t;
        const float4* ap = (const float4*)adj + g * 4;
        u32 mm = 0;
        #pragma unroll
        for (int w = 0; w < 4; w++) {
            float4 f = ap[w];
            mm |= (f.x > 0.f ? 1u : 0u) << (4 * w);
            mm |= (f.y > 0.f ? 1u : 0u) << (4 * w + 1);
            mm |= (f.z > 0.f ? 1u : 0u) << (4 * w + 2);
            mm |= (f.w > 0.f ? 1u : 0u) << (4 * w + 3);
        }
        maskH[g] = (u16)mm;
    } else if (id < 3072) {                 // feats -> feats2[d>>3][n][d&7]
        int n = (id - 2048) * 8 + (t >> 5), c = t & 31;
        const float* src = feats + (long)n * 256 + c * 8;
        float4 f0 = *(const float4*)src, f1 = *(const float4*)(src + 4);
        u16 tmp[8] = {f2bf(f0.x), f2bf(f0.y), f2bf(f0.z), f2bf(f0.w),
                      f2bf(f1.x), f2bf(f1.y), f2bf(f1.z), f2bf(f1.w)};
        *(int4*)&feats2[(long)c * 65536 + n * 8] = *(int4*)tmp;
    } else if (id < 3200) {                 // fc_w[256k][2048hd] -> fcw2[k>>3][hd][k&7]
        int b = id - 3072, bx = b & 31, by = b >> 5;
        float (*tt)[65] = (float(*)[65])shbuf;
        int c = t & 63, r0 = t >> 6;
        for (int rr = r0; rr < 64; rr += 4)
            tt[rr][c] = fc_w[(long)(by * 64 + rr) * 2048 + bx * 64 + c];
        __syncthreads();
        int hdl = t & 63;
        #pragma unroll
        for (int oo = 0; oo < 2; oo++) {
            int o = (t >> 6) + oo * 4;
            u16 tmp[8];
            #pragma unroll
            for (int e = 0; e < 8; e++) tmp[e] = f2bf(tt[o * 8 + e][hdl]);
            *(int4*)&fcw2[(long)(by * 8 + o) * 16384 + (bx * 64 + hdl) * 8] = *(int4*)tmp;
        }
    } else if (id < 3328) {                 // fp_w[2048k][256c] -> fpw2[k>>3][c][k&7]
        int b = id - 3200, bx = b & 3, by = b >> 2;
        float (*tt)[65] = (float(*)[65])shbuf;
        int c = t & 63, r0 = t >> 6;
        for (int rr = r0; rr < 64; rr += 4)
            tt[rr][c] = fp_w[(long)(by * 64 + rr) * 256 + bx * 64 + c];
        __syncthreads();
        int cl = t & 63;
        #pragma unroll
        for (int oo = 0; oo < 2; oo++) {
            int o = (t >> 6) + oo * 4;
            u16 tmp[8];
            #pragma unroll
            for (int e = 0; e < 8; e++) tmp[e] = f2bf(tt[o * 8 + e][cl]);
            *(int4*)&fpw2[(long)(by * 8 + o) * 2048 + (bx * 64 + cl) * 8] = *(int4*)tmp;
        }
    } else {                                // effective q/k weights
        int t2 = id - 3328, x = t2 & 15, dq = t2 >> 4;
        int h = x & 7, kind = x >> 3;
        const float* w = kind ? k_w : q_w;
        float* ws_ = shbuf;
        ws_[t] = w[t];
        __syncthreads();
        int dl = t >> 2, part = t & 3;
        int d = dq * 64 + dl;
        const float* row = fc_w + (long)d * 2048 + h * 256 + part * 64;
        float a = 0.f;
        #pragma unroll 8
        for (int i = 0; i < 64; i++) a += row[i] * ws_[part * 64 + i];
        a += __shfl_xor(a, 1);
        a += __shfl_xor(a, 2);
        if (part == 0) W[(long)x * 256 + d] = f2bf(a);
        if (t == 0 && dq == 0) {
            float cb = 0.f;
            const float* fb = fc_b + h * 256;
            for (int i = 0; i < 256; i++) cb += fb[i] * ws_[i];
            C[x] = cb + (kind ? k_b[0] : q_b[0]);
        }
    }
}

// ---- G1 (single-barrier DMA pipeline, LDS-transposed int4 epilogue)
// ---- + fused q/k MFMA blocks (outputs pre-scaled by log2 e) ----
__global__ __launch_bounds__(256)
void k_g1qk(const u16* __restrict__ fcw2, const u16* __restrict__ feats2,
            const float* __restrict__ bias, u16* __restrict__ V2,
            const u16* __restrict__ Wb, const float* __restrict__ C,
            float* __restrict__ qo, float* __restrict__ ko) {
    __shared__ u16 smem[16896];             // As 2x4096 | Bs 2x4096 ; eb 128x132
    int tid = threadIdx.x, wave = tid >> 6, lane = tid & 63;
    int q = lane >> 4, n16 = lane & 15;

    if (blockIdx.y >= 16) {                 // ---- q/k projection part ----
        int blk = (blockIdx.y - 16) * 64 + blockIdx.x;   // 0..127
        int rowBase = blk * 64 + wave * 16;
        floatx4 acc = {};
        #pragma unroll
        for (int k0 = 0; k0 < 256; k0 += 32) {
            short8 af = *(const short8*)&feats2[(long)((k0 >> 3) + q) * 65536
                                                + (rowBase + n16) * 8];
            short8 bf = *(const short8*)&Wb[n16 * 256 + k0 + q * 8];
            acc = __builtin_amdgcn_mfma_f32_16x16x32_bf16(af, bf, acc, 0, 0, 0);
        }
        float cc = C[n16];
        #pragma unroll
        for (int r = 0; r < 4; r++) {
            int gr = rowBase + q * 4 + r;
            int b = gr >> 10, nn = gr & 1023;
            float v = (acc[r] + cc) * LOG2E;        // pre-scale for v_exp in k_attn
            if (n16 < 8) qo[((b * 8 + n16) << 10) + nn] = v;
            else         ko[((b * 8 + (n16 - 8)) << 10) + nn] = v;
        }
        return;
    }

    int rowBase = blockIdx.y * 128;         // hd
    int colBase = blockIdx.x * 128;         // n
    int wr = wave >> 1, wc = wave & 1;
    floatx4 acc[4][4] = {};

    auto dma = [&](int k0, int p) {
        int kc = k0 >> 3;
        u16* Ab = smem + p * 4096;
        u16* Bb = smem + 8192 + p * 4096;
        #pragma unroll
        for (int r = 0; r < 2; r++) {
            __builtin_amdgcn_global_load_lds(
                (gp_t)&fcw2[(long)(kc + wave) * 16384 + (rowBase + r * 64 + lane) * 8],
                (sp_t)&Ab[(wave * 128 + r * 64 + lane) * 8], 16, 0, 0);
            __builtin_amdgcn_global_load_lds(
                (gp_t)&feats2[(long)(kc + wave) * 65536 + (colBase + r * 64 + lane) * 8],
                (sp_t)&Bb[(wave * 128 + r * 64 + lane) * 8], 16, 0, 0);
        }
    };

    dma(0, 0);
    __syncthreads();
    for (int k0 = 0; k0 < 256; k0 += 32) {
        int p = (k0 >> 5) & 1;
        u16* Ab = smem + p * 4096;
        u16* Bb = smem + 8192 + p * 4096;
        short8 af[4], bfr[4];
        #pragma unroll
        for (int i = 0; i < 4; i++)
            af[i] = *(short8*)&Ab[(q * 128 + wr * 64 + i * 16 + n16) * 8];
        #pragma unroll
        for (int i = 0; i < 4; i++)
            bfr[i] = *(short8*)&Bb[(q * 128 + wc * 64 + i * 16 + n16) * 8];
        if (k0 + 32 < 256) dma(k0 + 32, p ^ 1);
        #pragma unroll
        for (int mi = 0; mi < 4; mi++)
            #pragma unroll
            for (int ni = 0; ni < 4; ni++)
                acc[mi][ni] = __builtin_amdgcn_mfma_f32_16x16x32_bf16(
                    af[mi], bfr[ni], acc[mi][ni], 0, 0, 0);
        __syncthreads();
    }

    // ---- epilogue: stage bf16 tile [d_loc][nn_loc] in LDS (pitch 132),
    // ---- then coalesced int4 stores into k-grouped V2.
    u16* eb = smem;
    #pragma unroll
    for (int mi = 0; mi < 4; mi++) {
        #pragma unroll
        for (int r = 0; r < 4; r++) {
            int d_loc = wr * 64 + mi * 16 + q * 4 + r;
            float bv = bias[rowBase + d_loc];
            #pragma unroll
            for (int ni = 0; ni < 4; ni++) {
                int nn_loc = wc * 64 + ni * 16 + n16;
                eb[d_loc * 132 + nn_loc] = f2bf(acc[mi][ni][r] + bv);
            }
        }
    }
    __syncthreads();
    int hB = rowBase >> 8, dB = rowBase & 255;
    int bB = colBase >> 10, cB = (colBase & 1023) >> 3;
    long vbase = ((long)(bB * 8 + hB)) << 18;
    #pragma unroll
    for (int j = 0; j < 8; j++) {
        int idx = j * 256 + tid;
        int dl = idx & 127, c8 = idx >> 7;
        *(int4*)&V2[vbase + (long)(cB + c8) * 2048 + (dB + dl) * 8]
            = *(int4*)&eb[dl * 132 + c8 * 8];
    }
}

// -------- fused attention v8: raw v_exp (pre-scaled q/k), LDS-transposed
// -------- coalesced epilogue. Grid (64,8): x = bh (XCD locality). --------
__global__ __launch_bounds__(512)
__attribute__((amdgpu_waves_per_eu(4)))
void k_attn(const u32* __restrict__ maskW, const float* __restrict__ qv,
            const float* __restrict__ kv, const u16* __restrict__ fpjT2,
            u16* __restrict__ outh2) {
    __shared__ u16 smem[26624];           // As 2x5120 | Bs 2x8192 ; eb 128x132
    __shared__ float qS[128], kS[1024], lsumS[512], rlS[128];

    int z = blockIdx.x;                   // bh  (XCD = z % 8)
    int b = z >> 3, h = z & 7;
    int i0 = blockIdx.y * 128;
    int tid = threadIdx.x;
    int wave = tid >> 6, lane = tid & 63;
    int wr = wave >> 2, wc = wave & 3;    // 2 x 4 wave grid
    int q  = lane >> 4, n16 = lane & 15;

    if (tid < 256) *(float4*)&kS[tid * 4] = *(const float4*)&kv[(z << 10) + tid * 4];
    if (tid >= 256 && tid < 384) qS[tid - 256] = qv[(z << 10) + i0 + (tid - 256)];

    floatx4 acc[4][4] = {};
    int ar = tid >> 2;                    // P row (0..127)
    int jq = (tid & 3) * 8;               // P j-offset within BK
    const u32* mrow = maskW + (((long)(b << 10) + i0 + ar) << 5);
    const u16* Vbase = fpjT2 + ((long)z << 18);
    float lsum = 0.f;

    auto dma_v = [&](int k0, int p) {
        u16* Bb = smem + 10240 + p * 8192;
        #pragma unroll
        for (int t = 0; t < 2; t++) {
            int s = wave * 2 + t;         // 16 segments of 1 KB
            __builtin_amdgcn_global_load_lds(
                (gp_t)&Vbase[((k0 >> 3) + (s >> 2)) * 2048 + ((s & 3) * 64 + lane) * 8],
                (sp_t)&Bb[((s >> 2) * 256 + (s & 3) * 64 + lane) * 8],
                16, 0, 0);
        }
    };

    __syncthreads();                      // qS/kS visible
    float qi = qS[ar];

    auto stage_p = [&](int p, u32 mw, float4 kA, float4 kB) {
        u16* Ab = smem + p * 5120;
        float kk[8] = {kA.x, kA.y, kA.z, kA.w, kB.x, kB.y, kB.z, kB.w};
        u32 pw[4];
        #pragma unroll
        for (int e2 = 0; e2 < 4; e2++) {
            float s0 = qi + kk[2 * e2];
            s0 = fmaxf(s0, 0.01f * s0);               // leaky (log2-domain)
            float p0 = ((mw >> (2 * e2)) & 1u) ? exp2_raw(s0) : 0.f;
            float s1 = qi + kk[2 * e2 + 1];
            s1 = fmaxf(s1, 0.01f * s1);
            float p1 = ((mw >> (2 * e2 + 1)) & 1u) ? exp2_raw(s1) : 0.f;
            lsum += p0 + p1;
            pw[e2] = __builtin_amdgcn_perm(__float_as_uint(p1), __float_as_uint(p0),
                                           0x07060302);   // {bf16(p1),bf16(p0)}
        }
        *(int4*)&Ab[ar * 40 + jq] = *(int4*)&pw[0];
    };

    {
        u32 mw0 = mrow[0] >> jq;
        float4 kA0 = *(const float4*)&kS[jq];
        float4 kB0 = *(const float4*)&kS[jq + 4];
        dma_v(0, 0);
        stage_p(0, mw0, kA0, kB0);
    }
    __syncthreads();                      // iter 0 staged (DMA drained here)

    for (int k0 = 0; k0 < 1024; k0 += 32) {
        int p = (k0 >> 5) & 1;
        u16* Ab = smem + p * 5120;
        u16* Bb = smem + 10240 + p * 8192;
        int kn = (k0 + 32 < 1024) ? k0 + 32 : 0;
        u32 mw = mrow[kn >> 5] >> jq;     // prefetch next mask + k values
        float4 kA = *(const float4*)&kS[kn + jq];
        float4 kB = *(const float4*)&kS[kn + jq + 4];
        short8 af[4], bfr[4];
        #pragma unroll
        for (int i = 0; i < 4; i++)
            af[i] = *(short8*)&Ab[(wr * 64 + i * 16 + n16) * 40 + q * 8];
        #pragma unroll
        for (int i = 0; i < 4; i++)
            bfr[i] = *(short8*)&Bb[(q * 256 + wc * 64 + i * 16 + n16) * 8];
        if (k0 + 32 < 1024) {
            dma_v(k0 + 32, p ^ 1);
            stage_p(p ^ 1, mw, kA, kB);
        }
        #pragma unroll
        for (int mi = 0; mi < 4; mi++)
            #pragma unroll
            for (int ni = 0; ni < 4; ni++)
                acc[mi][ni] = __builtin_amdgcn_mfma_f32_16x16x32_bf16(
                    af[mi], bfr[ni], acc[mi][ni], 0, 0, 0);
        __syncthreads();                  // next buffer staged + DMA drained
    }

    lsumS[tid] = lsum;
    __syncthreads();
    if (tid < 128) {
        float l = lsumS[4 * tid] + lsumS[4 * tid + 1] +
                  lsumS[4 * tid + 2] + lsumS[4 * tid + 3];
        rlS[tid] = l > 0.f ? 1.f / l : 0.f;
    }
    __syncthreads();

    // ---- epilogue: 2 column-halves through LDS (pitch 132), int4 stores ----
    u16* eb = smem;
    long rowG = (long)(b * 1024 + i0);
    #pragma unroll
    for (int hh = 0; hh < 2; hh++) {
        if ((wc >> 1) == hh) {
            #pragma unroll
            for (int mi = 0; mi < 4; mi++) {
                #pragma unroll
                for (int r = 0; r < 4; r++) {
                    int grow = wr * 64 + mi * 16 + q * 4 + r;
                    float s = rlS[grow];
                    #pragma unroll
                    for (int ni = 0; ni < 4; ni++) {
                        int col = (wc & 1) * 64 + ni * 16 + n16;
                        eb[grow * 132 + col] = f2bf(acc[mi][ni][r] * s);
                    }
                }
            }
        }
        __syncthreads();
        #pragma unroll
        for (int j = 0; j < 4; j++) {
            int idx = j * 512 + tid;
            int row = idx & 127, c8 = idx >> 7;      // c8 0..15
            int chunk = h * 32 + hh * 16 + c8;
            *(int4*)&outh2[((long)chunk << 16) + (rowG + row) * 8]
                = *(int4*)&eb[row * 132 + c8 * 8];
        }
        __syncthreads();
    }
}

// -------- G3: 64x32 tiles, grid (128,8) = 4 blocks/CU; x=row-tile so the
// 8 col-siblings share an XCD (A2 L2-served). --------
__global__ __launch_bounds__(256)
void k_g3(const u16* __restrict__ A2,   // outh2 [256][8192][8]
          const u16* __restrict__ B2,   // fpw2  [256][256][8]
          const float* __restrict__ bias,
          const float* __restrict__ resid,
          float* __restrict__ out) {
    __shared__ u16 As[2][8 * 64 * 8];   // 8 KB / buf
    __shared__ u16 Bs[2][8 * 32 * 8];   // 4 KB / buf
    int rowBase = blockIdx.x * 64;
    int colBase = blockIdx.y * 32;
    int tid = threadIdx.x, wave = tid >> 6, lane = tid & 63;
    int q = lane >> 4, n16 = lane & 15;
    floatx4 acc[2] = {};

    auto dma = [&](int k0, int p) {
        int kc = k0 >> 3;
        #pragma unroll
        for (int t = 0; t < 2; t++) {
            int c = wave + t * 4;
            __builtin_amdgcn_global_load_lds(
                (gp_t)&A2[(long)(kc + c) * 65536 + (rowBase + lane) * 8],
                (sp_t)&As[p][(c * 64 + lane) * 8], 16, 0, 0);
        }
        __builtin_amdgcn_global_load_lds(
            (gp_t)&B2[(long)(kc + wave * 2 + (lane >> 5)) * 2048
                      + (colBase + (lane & 31)) * 8],
            (sp_t)&Bs[p][(wave * 64 + lane) * 8], 16, 0, 0);
    };

    dma(0, 0);
    __syncthreads();
    for (int k0 = 0; k0 < 2048; k0 += 64) {
        int p = (k0 >> 6) & 1;
        short8 af[2], bfr[2][2];
        #pragma unroll
        for (int kf = 0; kf < 2; kf++) {
            af[kf] = *(short8*)&As[p][((kf * 4 + q) * 64 + wave * 16 + n16) * 8];
            #pragma unroll
            for (int nf = 0; nf < 2; nf++)
                bfr[kf][nf] = *(short8*)&Bs[p][((kf * 4 + q) * 32 + nf * 16 + n16) * 8];
        }
        if (k0 + 64 < 2048) dma(k0 + 64, p ^ 1);
        #pragma unroll
        for (int kf = 0; kf < 2; kf++)
            #pragma unroll
            for (int nf = 0; nf < 2; nf++)
                acc[nf] = __builtin_amdgcn_mfma_f32_16x16x32_bf16(
                    af[kf], bfr[kf][nf], acc[nf], 0, 0, 0);
        __syncthreads();
    }

    #pragma unroll
    for (int nf = 0; nf < 2; nf++) {
        #pragma unroll
        for (int r = 0; r < 4; r++) {
            int grow = rowBase + wave * 16 + q * 4 + r;
            int gcol = colBase + nf * 16 + n16;
            float v = acc[nf][r] + bias[gcol] + resid[(long)grow * 256 + gcol];
            out[(long)grow * 256 + gcol] = 1.f / (1.f + __expf(-v));
        }
    }
}

extern "C" void kernel_launch(void* const* d_in, const int* in_sizes, int n_in,
                              void* d_out, int out_size, void* d_ws, size_t ws_size,
                              hipStream_t stream) {
    const float* feats = (const float*)d_in[0];
    const float* adj   = (const float*)d_in[1];
    const float* fc_w  = (const float*)d_in[2];
    const float* fc_b  = (const float*)d_in[3];
    const float* q_w   = (const float*)d_in[4];
    const float* q_b   = (const float*)d_in[5];
    const float* k_w   = (const float*)d_in[6];
    const float* k_b   = (const float*)d_in[7];
    const float* fp_w  = (const float*)d_in[8];
    const float* fp_b  = (const float*)d_in[9];

    char* ws = (char*)d_ws;
    u16*   feats2 = (u16*)ws;   ws += (size_t)2097152 * 2;   // [d>>3][n][d&7]
    u16*   fcw2   = (u16*)ws;   ws += (size_t)524288 * 2;    // [k>>3][hd][k&7]
    u16*   fpw2   = (u16*)ws;   ws += (size_t)524288 * 2;    // [k>>3][col][k&7]
    u16*   fpjT2  = (u16*)ws;   ws += (size_t)16777216 * 2;  // V2 [bh][n>>3][d][n&7]
    float* qv     = (float*)ws; ws += (size_t)65536 * 4;     // [b,h,n] (*log2e)
    float* kv     = (float*)ws; ws += (size_t)65536 * 4;
    u16*   outh2  = (u16*)ws;   ws += (size_t)16777216 * 2;  // [k>>3][row][k&7]
    u64*   maskB  = (u64*)ws;   ws += (size_t)131072 * 8;    // adj bits, 1 MB
    u16*   Weff   = (u16*)ws;   ws += (size_t)4096 * 2;      // [16][256] bf16
    float* Ceff   = (float*)ws; ws += (size_t)16 * 4;        // per-head consts

    k_prepall<<<3392, 256, 0, stream>>>(feats, adj, fc_w, fc_b, q_w, q_b,
                                        k_w, k_b, fp_w,
                                        feats2, (u16*)maskB, fcw2, fpw2, Weff, Ceff);

    k_g1qk<<<dim3(64, 18), 256, 0, stream>>>(fcw2, feats2, fc_b, fpjT2,
                                             Weff, Ceff, qv, kv);

    k_attn<<<dim3(64, 8), 512, 0, stream>>>((const u32*)maskB, qv, kv, fpjT2, outh2);

    k_g3<<<dim3(128, 8), 256, 0, stream>>>(outh2, fpw2, fp_b, feats, (float*)d_out);
}